// Round 5
// baseline (4892.815 us; speedup 1.0000x reference)
//
#include <hip/hip_runtime.h>
#include <hip/hip_bf16.h>

#define Bb    128
#define Ss    256
#define Ff    4
#define Vv    1024
#define Ee    512
#define Hh    1024
#define FourH 4096
#define Mrows (Bb * Ss)
#define NBLK  192      // 64 layer-0 WGs + 128 layer-1 WGs
#define NGRP  8
#define GSZ   (NBLK / NGRP)   // 24

typedef _Float16 f16;
typedef __attribute__((ext_vector_type(8))) _Float16 half8;
typedef __attribute__((ext_vector_type(4))) float f32x4;

// ---------------------------------------------------------------------------
__global__ void cvt_f16_kernel(const float* __restrict__ s, f16* __restrict__ d, int n) {
    int i = blockIdx.x * blockDim.x + threadIdx.x;
    int stride = gridDim.x * blockDim.x;
    for (; i < n; i += stride) d[i] = (f16)s[i];
}

__global__ void bias_combine_kernel(const float* __restrict__ a, const float* __restrict__ b,
                                    const float* __restrict__ c, const float* __restrict__ d,
                                    float* __restrict__ o0, float* __restrict__ o1) {
    int i = blockIdx.x * blockDim.x + threadIdx.x;
    if (i < FourH) o0[i] = a[i] + b[i];
    else if (i < 2 * FourH) { int j = i - FourH; o1[j] = c[j] + d[j]; }
}

// Embedding: sum over F tables -> f16 [S, B, E] (time-major)
__global__ void emb_kernel(const int* __restrict__ x, const float* __restrict__ emb,
                           f16* __restrict__ out) {
    int r = blockIdx.x;
    int t = threadIdx.x;
    int b = r / Ss, s = r % Ss;
    const int* xr = x + (size_t)r * Ff;
    const float* e0 = emb + (size_t)xr[0] * Ee;
    const float* e1 = emb + (size_t)(Vv + xr[1]) * Ee;
    const float* e2 = emb + (size_t)(2 * Vv + xr[2]) * Ee;
    const float* e3 = emb + (size_t)(3 * Vv + xr[3]) * Ee;
    f16* orow = out + (size_t)(s * Bb + b) * Ee;
    for (int e = t; e < Ee; e += 256) orow[e] = (f16)(e0[e] + e1[e] + e2[e] + e3[e]);
}

// ---------------------------------------------------------------------------
// C[M,N] = A[M,K] @ B[N,K]^T + bias[N]  (f16 in, f16 out, fp32 accum)
#define BM 128
#define BN 128
#define BK 32
#define LDP 40

__global__ __launch_bounds__(256) void gemm_bt_kernel(
    const f16* __restrict__ A, const f16* __restrict__ Bw,
    const float* __restrict__ bias, f16* __restrict__ C,
    int M, int N, int K)
{
    __shared__ f16 As[BM * LDP];
    __shared__ f16 Bs[BN * LDP];
    int tid  = threadIdx.x;
    int n0   = blockIdx.x * BN;
    int m0   = blockIdx.y * BM;
    int w    = tid >> 6, lane = tid & 63;
    int wm   = (w >> 1) * 64, wn = (w & 1) * 64;
    int lrow = lane & 15, koff = lane >> 4;

    f32x4 acc[4][4] = {};

    for (int kb = 0; kb < K; kb += BK) {
        __syncthreads();
        #pragma unroll
        for (int h = 0; h < 2; ++h) {
            int ch  = tid + h * 256;
            int row = ch >> 2;
            int cc  = (ch & 3) * 8;
            *reinterpret_cast<uint4*>(&As[row * LDP + cc]) =
                *reinterpret_cast<const uint4*>(A + (size_t)(m0 + row) * K + kb + cc);
            *reinterpret_cast<uint4*>(&Bs[row * LDP + cc]) =
                *reinterpret_cast<const uint4*>(Bw + (size_t)(n0 + row) * K + kb + cc);
        }
        __syncthreads();
        half8 af[4], bf[4];
        #pragma unroll
        for (int mt = 0; mt < 4; ++mt)
            af[mt] = *reinterpret_cast<const half8*>(&As[(wm + mt * 16 + lrow) * LDP + koff * 8]);
        #pragma unroll
        for (int nt = 0; nt < 4; ++nt)
            bf[nt] = *reinterpret_cast<const half8*>(&Bs[(wn + nt * 16 + lrow) * LDP + koff * 8]);
        #pragma unroll
        for (int mt = 0; mt < 4; ++mt)
            #pragma unroll
            for (int nt = 0; nt < 4; ++nt)
                acc[mt][nt] = __builtin_amdgcn_mfma_f32_16x16x32_f16(af[mt], bf[nt], acc[mt][nt], 0, 0, 0);
    }

    #pragma unroll
    for (int mt = 0; mt < 4; ++mt)
        #pragma unroll
        for (int nt = 0; nt < 4; ++nt) {
            int col = n0 + wn + nt * 16 + lrow;
            float bv = bias[col];
            #pragma unroll
            for (int r = 0; r < 4; ++r) {
                int rowg = m0 + wm + mt * 16 + koff * 4 + r;
                C[(size_t)rowg * N + col] = (f16)(acc[mt][nt][r] + bv);
            }
        }
}

// ---------------------------------------------------------------------------
__device__ __forceinline__ void gload_lds16(const void* g, void* l) {
    __builtin_amdgcn_global_load_lds((const __attribute__((address_space(1))) void*)g,
                                     (__attribute__((address_space(3))) void*)l, 16, 0, 0);
}

__device__ __forceinline__ unsigned aload(unsigned* p) {
    return __hip_atomic_load(p, __ATOMIC_RELAXED, __HIP_MEMORY_SCOPE_AGENT);
}

// 2-level device-scope grid barrier. Monotonic generation counters.
__device__ __forceinline__ void grid_sync(unsigned* bar, int wg) {
    __syncthreads();
    if (threadIdx.x == 0) {
        const int g = wg & (NGRP - 1);
        unsigned* arr  = bar + g * 32;
        unsigned* rel  = bar + (8 + g) * 32;
        unsigned* root = bar + 16 * 32;
        unsigned* rrel = bar + 17 * 32;
        __threadfence();
        unsigned a   = atomicAdd(arr, 1u);
        unsigned gen = a / (unsigned)GSZ;
        if (a % (unsigned)GSZ == (unsigned)(GSZ - 1)) {       // group leader this gen
            unsigned r = atomicAdd(root, 1u);
            if (r % (unsigned)NGRP == (unsigned)(NGRP - 1)) {
                atomicAdd(rrel, 1u);                          // global release
            } else {
                while (aload(rrel) < gen + 1u) __builtin_amdgcn_s_sleep(2);
            }
            atomicAdd(rel, 1u);                               // group release
        }
        while (aload(rel) < gen + 1u) __builtin_amdgcn_s_sleep(2);
        __threadfence();
    }
    __syncthreads();
}

__device__ __forceinline__ float sigm(float v) { return 1.f / (1.f + __expf(-v)); }

// ---------------------------------------------------------------------------
// Persistent fused 2-layer LSTM scan. Iteration i: L0 computes step i (i<256),
// L1 computes step i-1 (i>=1). Weights held in registers for the whole launch.
//
// R5: fixes R4's fatal slab-size bug (64 rows x 512 B = 32 KB, not 16 KB).
// L1 waves stream their 32 KB K-window through a 16 KB ring (2 x 8 KB bufs of
// 16 rows): stage r0-15/r16-31 up front; per 16-row block: vmcnt(8) ->
// ds_read x8 -> lgkmcnt(0) -> restage buffer with next 16 rows -> 32 MFMAs;
// last block waits vmcnt(0). No __syncthreads in the whole L1 GEMM phase.
// ep 8-way reduction in each wave's own slab (16 KB exactly), one barrier.
// WGs 0..63: L0 (rowg2 x ug32; 64 rows, 32 units) - R3-verified structure.
// WGs 64..191: L1 (rowg2 x ug64; 64 rows, 16 units, K=2048=[wih1;whh1],
//              waves = pure kq(8), 256-col K-windows).
__global__ __launch_bounds__(512, 2) __attribute__((amdgpu_waves_per_eu(2, 2)))
void scan_kernel(
    const f16* __restrict__ gx0,    // gates0 chunk base [nt][128][4096]
    int t_begin, int t_end,
    const f16* __restrict__ wih1, const f16* __restrict__ whh0,
    const f16* __restrict__ whh1, const float* __restrict__ bias1,
    f16* __restrict__ h0a, f16* __restrict__ h0b,
    f16* __restrict__ h1a, f16* __restrict__ h1b,
    float* __restrict__ c0, float* __restrict__ c1,
    float* __restrict__ out, unsigned* __restrict__ bar)
{
    __shared__ __align__(1024) char smem[131072];
    float* ep = (float*)smem;

    const int tid  = threadIdx.x;
    const int wg   = blockIdx.x;
    const int lane = tid & 63;
    const int w    = tid >> 6;
    const int lrow = lane & 15, koff = lane >> 4;
    const unsigned swz   = (unsigned)((lane & 7) << 4);
    const unsigned e0s   = ((unsigned)(koff * 16)) ^ swz;         // (kc&1)==0
    const unsigned e1s   = ((unsigned)(64 + koff * 16)) ^ swz;    // (kc&1)==1
    const unsigned lane16 = (unsigned)(lane << 4);

    if (wg < 64) {
        // ---------------- Layer 0: rowg(2) x ug(32 units), waves np(4) x kh(2)
        const int rowg = wg >> 5, ug = wg & 31;
        const int np = w & 3, kh = w >> 2;
        const int u0 = ug * 32;
        const size_t growb = (size_t)rowg * 64;
        const int cw = np * 32 + lrow;         // + nt*16

        half8 wreg[16][2];
        #pragma unroll
        for (int kc = 0; kc < 16; ++kc)
            #pragma unroll
            for (int nt = 0; nt < 2; ++nt) {
                int c = cw + nt * 16;
                wreg[kc][nt] = *(const half8*)(whh0
                    + (size_t)((c >> 5) * Hh + u0 + (c & 31)) * Hh
                    + kh * 512 + kc * 32 + koff * 8);
            }

        float creg[4];
        #pragma unroll
        for (int q = 0; q < 4; ++q) {
            int p = tid + q * 512, row = p >> 5, uu = p & 31;
            creg[q] = c0[(growb + row) * Hh + u0 + uu];
        }

        for (int i = t_begin; i < t_end; ++i) {
            if (i < 256) {
                const f16* hp = (i & 1) ? h0a : h0b;   // h0[i-1]
                f16*       hw = (i & 1) ? h0b : h0a;   // h0[i]
                const f16* gx = gx0 + (size_t)(i - t_begin) * (Bb * FourH);
                const char* hb = (const char*)hp + growb * 2048;

                // single-shot stage: 64 rows x 2048 B (16 instr/wave)
                #pragma unroll
                for (int t = 0; t < 16; ++t) {
                    int row  = w * 8 + (t >> 1);
                    int half = t & 1;
                    gload_lds16(hb + (size_t)row * 2048 + half * 1024
                                   + (lane16 ^ ((unsigned)((row & 7) << 4))),
                                smem + row * 2048 + half * 1024);
                }
                // gate-input prefetch (retires with the same vmcnt wait)
                f16 gxr[4][4];
                #pragma unroll
                for (int q = 0; q < 4; ++q) {
                    int p = tid + q * 512, row = p >> 5, uu = p & 31;
                    const f16* gr = gx + (growb + row) * FourH + u0 + uu;
                    gxr[q][0] = gr[0];      gxr[q][1] = gr[Hh];
                    gxr[q][2] = gr[2 * Hh]; gxr[q][3] = gr[3 * Hh];
                }

                asm volatile("s_waitcnt vmcnt(0)" ::: "memory");
                __syncthreads();

                f32x4 acc[4][2] = {};
                #pragma unroll
                for (int kc = 0; kc < 16; ++kc) {
                    unsigned off = (unsigned)(kh * 1024 + (kc >> 1) * 128)
                                 + ((kc & 1) ? e1s : e0s);
                    half8 a[4];
                    #pragma unroll
                    for (int mt = 0; mt < 4; ++mt)
                        a[mt] = *(const half8*)(smem + (mt * 16 + lrow) * 2048 + off);
                    #pragma unroll
                    for (int mt = 0; mt < 4; ++mt) {
                        acc[mt][0] = __builtin_amdgcn_mfma_f32_16x16x32_f16(a[mt], wreg[kc][0], acc[mt][0], 0, 0, 0);
                        acc[mt][1] = __builtin_amdgcn_mfma_f32_16x16x32_f16(a[mt], wreg[kc][1], acc[mt][1], 0, 0, 0);
                    }
                }
                __syncthreads();           // staging reads done before ep overwrite
                // ep[kh][row][c] : [2][64][128]
                #pragma unroll
                for (int mt = 0; mt < 4; ++mt)
                    #pragma unroll
                    for (int nt = 0; nt < 2; ++nt) {
                        int c = cw + nt * 16;
                        int rowb = mt * 16 + koff * 4;
                        #pragma unroll
                        for (int r = 0; r < 4; ++r)
                            ep[(kh * 64 + rowb + r) * 128 + c] = acc[mt][nt][r];
                    }
                __syncthreads();
                #pragma unroll
                for (int q = 0; q < 4; ++q) {
                    int p = tid + q * 512, row = p >> 5, uu = p & 31;
                    float ipre = ep[row * 128 + uu]        + ep[(64 + row) * 128 + uu]        + (float)gxr[q][0];
                    float fpre = ep[row * 128 + 32 + uu]   + ep[(64 + row) * 128 + 32 + uu]   + (float)gxr[q][1];
                    float gpre = ep[row * 128 + 64 + uu]   + ep[(64 + row) * 128 + 64 + uu]   + (float)gxr[q][2];
                    float opre = ep[row * 128 + 96 + uu]   + ep[(64 + row) * 128 + 96 + uu]   + (float)gxr[q][3];
                    float cn = sigm(fpre) * creg[q] + sigm(ipre) * tanhf(gpre);
                    creg[q] = cn;
                    hw[(growb + row) * Hh + u0 + uu] = (f16)(sigm(opre) * tanhf(cn));
                }
            }
            grid_sync(bar, wg);
        }
        #pragma unroll
        for (int q = 0; q < 4; ++q) {
            int p = tid + q * 512, row = p >> 5, uu = p & 31;
            c0[(growb + row) * Hh + u0 + uu] = creg[q];
        }
    } else {
        // ---------------- Layer 1: rowg(2) x ug(64; 16 units), waves = pure kq(8)
        const int wgl = wg - 64;
        const int rowg = wgl >> 6, ug = wgl & 63;
        const int kq = w;                      // 0..7 : K-window kq*256 of 2048
        const int u0 = ug * 16;
        const size_t growb = (size_t)rowg * 64;
        const int l7 = lane & 7;

        const f16* wbase = (kq < 4) ? wih1 : whh1;
        half8 wreg[8][4];                      // [kc][nt], K = (kq&3)*256 + kc*32
        #pragma unroll
        for (int kc = 0; kc < 8; ++kc)
            #pragma unroll
            for (int nt = 0; nt < 4; ++nt)     // col = nt*16+lrow: gate=nt, unit=lrow
                wreg[kc][nt] = *(const half8*)(wbase
                    + (size_t)(nt * Hh + u0 + lrow) * Hh
                    + (kq & 3) * 256 + kc * 32 + koff * 8);

        float creg[2];
        #pragma unroll
        for (int q = 0; q < 2; ++q) {
            int p = tid + q * 512, row = p >> 4, uu = p & 15;
            creg[q] = c1[(growb + row) * Hh + u0 + uu];
        }
        const int ub = tid & 15;
        float b0 = bias1[u0 + ub], b1 = bias1[Hh + u0 + ub],
              b2 = bias1[2 * Hh + u0 + ub], b3 = bias1[3 * Hh + u0 + ub];

        const unsigned wb = (unsigned)kq * 16384u;   // this wave's 16 KB LDS slab
        const int r2 = lane >> 5;                    // 0/1 (row parity per instr)
        const int chs0 = lane & 31;                  // 16B-chunk slot in 512B row

        // stage 16 rows (rb_..rb_+15) into buf at byte offset bo_ (8 instrs;
        // each instr covers 2 rows: lanes 0-31 -> row, 32-63 -> row+1)
        #define STG(rb_, bo_) { \
            _Pragma("unroll") \
            for (int t = 0; t < 8; ++t) { \
                int rl = (rb_) + t * 2 + r2; \
                gload_lds16(src + (size_t)rl * 2048 \
                                + ((unsigned)((chs0 ^ (rl & 7)) << 4)), \
                            smem + wb + (bo_) + (unsigned)(t * 1024)); \
            } }
        // compute one 16-row block from buf bo_ into acc[mt_]
        #define CMT(mt_, bo_) { \
            _Pragma("unroll") \
            for (int kc = 0; kc < 8; ++kc) { \
                half8 a = *(const half8*)(smem + wb + (bo_) \
                            + (unsigned)(lrow * 512) \
                            + ((unsigned)(((kc * 4 + koff) ^ l7) << 4))); \
                acc[mt_][0] = __builtin_amdgcn_mfma_f32_16x16x32_f16(a, wreg[kc][0], acc[mt_][0], 0, 0, 0); \
                acc[mt_][1] = __builtin_amdgcn_mfma_f32_16x16x32_f16(a, wreg[kc][1], acc[mt_][1], 0, 0, 0); \
                acc[mt_][2] = __builtin_amdgcn_mfma_f32_16x16x32_f16(a, wreg[kc][2], acc[mt_][2], 0, 0, 0); \
                acc[mt_][3] = __builtin_amdgcn_mfma_f32_16x16x32_f16(a, wreg[kc][3], acc[mt_][3], 0, 0, 0); \
            } }

        for (int i = t_begin; i < t_end; ++i) {
            int t1 = i - 1;
            if (t1 >= 0) {
                const f16* a0 = (t1 & 1) ? h0b : h0a;  // h0[t1]
                const f16* a1 = (t1 & 1) ? h1a : h1b;  // h1[t1-1]
                f16*       hw = (t1 & 1) ? h1b : h1a;  // h1[t1]
                const char* src = ((kq < 4) ? (const char*)a0 : (const char*)a1)
                                + growb * 2048 + (size_t)(kq & 3) * 512;

                f32x4 acc[4][4] = {};
                STG(0, 0u)
                STG(16, 8192u)
                asm volatile("s_waitcnt vmcnt(8)" ::: "memory");   // rows 0-15 in
                CMT(0, 0u)
                asm volatile("s_waitcnt lgkmcnt(0)" ::: "memory"); // buf0 reads done
                STG(32, 0u)
                asm volatile("s_waitcnt vmcnt(8)" ::: "memory");   // rows 16-31 in
                CMT(1, 8192u)
                asm volatile("s_waitcnt lgkmcnt(0)" ::: "memory"); // buf1 reads done
                STG(48, 8192u)
                asm volatile("s_waitcnt vmcnt(8)" ::: "memory");   // rows 32-47 in
                CMT(2, 0u)
                asm volatile("s_waitcnt vmcnt(0)" ::: "memory");   // rows 48-63 in
                CMT(3, 8192u)

                // ep partials into OWN slab (64 rows x 64 cols f32 = 16 KB).
                // layout: slab[row*256 + (c ^ (sw<<4))*4], sw=(row^(row>>2))&3
                #pragma unroll
                for (int mt = 0; mt < 4; ++mt)
                    #pragma unroll
                    for (int nt = 0; nt < 4; ++nt) {
                        int c = nt * 16 + lrow;
                        #pragma unroll
                        for (int r = 0; r < 4; ++r) {
                            int row = mt * 16 + koff * 4 + r;
                            int sw  = (row ^ (row >> 2)) & 3;
                            *(float*)(smem + wb + (unsigned)(row * 256)
                                      + (unsigned)((c ^ (sw << 4)) * 4)) = acc[mt][nt][r];
                        }
                    }
                __syncthreads();
                #pragma unroll
                for (int q = 0; q < 2; ++q) {
                    int p = tid + q * 512, row = p >> 4, uu = p & 15;
                    int sw = (row ^ (row >> 2)) & 3;
                    unsigned rb = (unsigned)(row * 256);
                    float s0 = b0, s1 = b1, s2 = b2, s3 = b3;
                    #pragma unroll
                    for (int k8 = 0; k8 < 8; ++k8) {
                        const char* base = smem + (unsigned)k8 * 16384u + rb;
                        s0 += *(const float*)(base + (unsigned)((( 0 + uu) ^ (sw << 4)) * 4));
                        s1 += *(const float*)(base + (unsigned)(((16 + uu) ^ (sw << 4)) * 4));
                        s2 += *(const float*)(base + (unsigned)(((32 + uu) ^ (sw << 4)) * 4));
                        s3 += *(const float*)(base + (unsigned)(((48 + uu) ^ (sw << 4)) * 4));
                    }
                    float cn = sigm(s1) * creg[q] + sigm(s0) * tanhf(s2);
                    creg[q] = cn;
                    float hn = sigm(s3) * tanhf(cn);
                    hw[(growb + row) * Hh + u0 + uu] = (f16)hn;
                    out[(growb + row) * (size_t)(Ss * Hh) + (size_t)t1 * Hh + u0 + uu] = hn;
                }
            }
            grid_sync(bar, wg);
        }
        #pragma unroll
        for (int q = 0; q < 2; ++q) {
            int p = tid + q * 512, row = p >> 4, uu = p & 15;
            c1[(growb + row) * Hh + u0 + uu] = creg[q];
        }
        #undef STG
        #undef CMT
    }
}

// ---------------------------------------------------------------------------
extern "C" void kernel_launch(void* const* d_in, const int* in_sizes, int n_in,
                              void* d_out, int out_size, void* d_ws, size_t ws_size,
                              hipStream_t stream) {
    const int*   x      = (const int*)  d_in[0];
    const float* emb    = (const float*)d_in[1];
    const float* proj_w = (const float*)d_in[2];
    const float* proj_b = (const float*)d_in[3];
    const float* W_ih0  = (const float*)d_in[4];
    const float* W_hh0  = (const float*)d_in[5];
    const float* b_ih0  = (const float*)d_in[6];
    const float* b_hh0  = (const float*)d_in[7];
    const float* W_ih1  = (const float*)d_in[8];
    const float* W_hh1  = (const float*)d_in[9];
    const float* b_ih1  = (const float*)d_in[10];
    const float* b_hh1  = (const float*)d_in[11];
    float* out = (float*)d_out;

    char* ws = (char*)d_ws;
    f16* emb_sum = (f16*)(ws);                               // 32 MB [S,B,E]
    f16* x_in    = (f16*)(ws + 33554432ull);                 // 32 MB [S,B,E]
    f16* gates   = (f16*)(ws + 67108864ull);                 // 128 MB (128-step chunk)
    char* wp     = ws + 201326592ull;
    f16* pw_f   = (f16*)wp; wp += (size_t)Ee * Ee * 2;
    f16* wih0_f = (f16*)wp; wp += (size_t)FourH * Ee * 2;
    f16* whh0_f = (f16*)wp; wp += (size_t)FourH * Hh * 2;
    f16* wih1_f = (f16*)wp; wp += (size_t)FourH * Hh * 2;
    f16* whh1_f = (f16*)wp; wp += (size_t)FourH * Hh * 2;
    float* bias0 = (float*)wp; wp += FourH * 4;
    float* bias1 = (float*)wp; wp += FourH * 4;
    char* zbase = wp;
    f16*   h0a = (f16*)wp;   wp += (size_t)Bb * Hh * 2;
    f16*   h0b = (f16*)wp;   wp += (size_t)Bb * Hh * 2;
    f16*   h1a = (f16*)wp;   wp += (size_t)Bb * Hh * 2;
    f16*   h1b = (f16*)wp;   wp += (size_t)Bb * Hh * 2;
    float* c0  = (float*)wp; wp += (size_t)Bb * Hh * 4;
    float* c1  = (float*)wp; wp += (size_t)Bb * Hh * 4;
    unsigned* bar = (unsigned*)wp; wp += 4096;               // 2-level barrier counters
    size_t zbytes = (size_t)(wp - zbase);

    // Prologue: converts, biases, zero state+barrier
    cvt_f16_kernel<<<512, 256, 0, stream>>>(proj_w, pw_f,   Ee * Ee);
    cvt_f16_kernel<<<512, 256, 0, stream>>>(W_ih0,  wih0_f, FourH * Ee);
    cvt_f16_kernel<<<512, 256, 0, stream>>>(W_hh0,  whh0_f, FourH * Hh);
    cvt_f16_kernel<<<512, 256, 0, stream>>>(W_ih1,  wih1_f, FourH * Hh);
    cvt_f16_kernel<<<512, 256, 0, stream>>>(W_hh1,  whh1_f, FourH * Hh);
    bias_combine_kernel<<<32, 256, 0, stream>>>(b_ih0, b_hh0, b_ih1, b_hh1, bias0, bias1);
    hipMemsetAsync(zbase, 0, zbytes, stream);

    // Embedding + input projection (time-major)
    emb_kernel<<<Mrows, 256, 0, stream>>>(x, emb, emb_sum);
    gemm_bt_kernel<<<dim3(Ee / BN, Mrows / BM), 256, 0, stream>>>(
        emb_sum, pw_f, proj_b, x_in, Mrows, Ee, Ee);

    // Two half-sequence passes: gates0 GEMM chunk + cooperative scan
    const int CM = Mrows / 2;   // 16384 rows = 128 steps

    for (int half = 0; half < 2; ++half) {
        gemm_bt_kernel<<<dim3(FourH / BN, CM / BM), 256, 0, stream>>>(
            x_in + (size_t)half * CM * Ee, wih0_f, bias0, gates, CM, FourH, Ee);
        int tb = half * 128;
        int te = (half == 0) ? 128 : 257;   // second pass runs one extra L1-only iter
        const f16* gxp = gates;
        void* args[] = { (void*)&gxp, (void*)&tb, (void*)&te,
                         (void*)&wih1_f, (void*)&whh0_f, (void*)&whh1_f, (void*)&bias1,
                         (void*)&h0a, (void*)&h0b, (void*)&h1a, (void*)&h1b,
                         (void*)&c0, (void*)&c1, (void*)&out, (void*)&bar };
        hipLaunchCooperativeKernel((const void*)scan_kernel, dim3(NBLK), dim3(512),
                                   args, 0, stream);
    }
}

// Round 7
// 3118.834 us; speedup vs baseline: 1.5688x; 1.5688x over previous
//
#include <hip/hip_runtime.h>
#include <hip/hip_bf16.h>

#define Bb    128
#define Ss    256
#define Ff    4
#define Vv    1024
#define Ee    512
#define Hh    1024
#define FourH 4096
#define Mrows (Bb * Ss)
#define NBLK  192      // 64 layer-0 WGs + 128 layer-1 WGs
#define NGRP  8
#define GSZ   (NBLK / NGRP)   // 24

typedef _Float16 f16;
typedef __attribute__((ext_vector_type(8))) _Float16 half8;
typedef __attribute__((ext_vector_type(4))) float f32x4;

// ---------------------------------------------------------------------------
__global__ void cvt_f16_kernel(const float* __restrict__ s, f16* __restrict__ d, int n) {
    int i = blockIdx.x * blockDim.x + threadIdx.x;
    int stride = gridDim.x * blockDim.x;
    for (; i < n; i += stride) d[i] = (f16)s[i];
}

__global__ void bias_combine_kernel(const float* __restrict__ a, const float* __restrict__ b,
                                    const float* __restrict__ c, const float* __restrict__ d,
                                    float* __restrict__ o0, float* __restrict__ o1) {
    int i = blockIdx.x * blockDim.x + threadIdx.x;
    if (i < FourH) o0[i] = a[i] + b[i];
    else if (i < 2 * FourH) { int j = i - FourH; o1[j] = c[j] + d[j]; }
}

// Embedding: sum over F tables -> f16 [S, B, E] (time-major)
__global__ void emb_kernel(const int* __restrict__ x, const float* __restrict__ emb,
                           f16* __restrict__ out) {
    int r = blockIdx.x;
    int t = threadIdx.x;
    int b = r / Ss, s = r % Ss;
    const int* xr = x + (size_t)r * Ff;
    const float* e0 = emb + (size_t)xr[0] * Ee;
    const float* e1 = emb + (size_t)(Vv + xr[1]) * Ee;
    const float* e2 = emb + (size_t)(2 * Vv + xr[2]) * Ee;
    const float* e3 = emb + (size_t)(3 * Vv + xr[3]) * Ee;
    f16* orow = out + (size_t)(s * Bb + b) * Ee;
    for (int e = t; e < Ee; e += 256) orow[e] = (f16)(e0[e] + e1[e] + e2[e] + e3[e]);
}

// ---------------------------------------------------------------------------
// C[M,N] = A[M,K] @ B[N,K]^T + bias[N]  (f16 in, f16 out, fp32 accum)
#define BM 128
#define BN 128
#define BK 32
#define LDP 40

__global__ __launch_bounds__(256) void gemm_bt_kernel(
    const f16* __restrict__ A, const f16* __restrict__ Bw,
    const float* __restrict__ bias, f16* __restrict__ C,
    int M, int N, int K)
{
    __shared__ f16 As[BM * LDP];
    __shared__ f16 Bs[BN * LDP];
    int tid  = threadIdx.x;
    int n0   = blockIdx.x * BN;
    int m0   = blockIdx.y * BM;
    int w    = tid >> 6, lane = tid & 63;
    int wm   = (w >> 1) * 64, wn = (w & 1) * 64;
    int lrow = lane & 15, koff = lane >> 4;

    f32x4 acc[4][4] = {};

    for (int kb = 0; kb < K; kb += BK) {
        __syncthreads();
        #pragma unroll
        for (int h = 0; h < 2; ++h) {
            int ch  = tid + h * 256;
            int row = ch >> 2;
            int cc  = (ch & 3) * 8;
            *reinterpret_cast<uint4*>(&As[row * LDP + cc]) =
                *reinterpret_cast<const uint4*>(A + (size_t)(m0 + row) * K + kb + cc);
            *reinterpret_cast<uint4*>(&Bs[row * LDP + cc]) =
                *reinterpret_cast<const uint4*>(Bw + (size_t)(n0 + row) * K + kb + cc);
        }
        __syncthreads();
        half8 af[4], bf[4];
        #pragma unroll
        for (int mt = 0; mt < 4; ++mt)
            af[mt] = *reinterpret_cast<const half8*>(&As[(wm + mt * 16 + lrow) * LDP + koff * 8]);
        #pragma unroll
        for (int nt = 0; nt < 4; ++nt)
            bf[nt] = *reinterpret_cast<const half8*>(&Bs[(wn + nt * 16 + lrow) * LDP + koff * 8]);
        #pragma unroll
        for (int mt = 0; mt < 4; ++mt)
            #pragma unroll
            for (int nt = 0; nt < 4; ++nt)
                acc[mt][nt] = __builtin_amdgcn_mfma_f32_16x16x32_f16(af[mt], bf[nt], acc[mt][nt], 0, 0, 0);
    }

    #pragma unroll
    for (int mt = 0; mt < 4; ++mt)
        #pragma unroll
        for (int nt = 0; nt < 4; ++nt) {
            int col = n0 + wn + nt * 16 + lrow;
            float bv = bias[col];
            #pragma unroll
            for (int r = 0; r < 4; ++r) {
                int rowg = m0 + wm + mt * 16 + koff * 4 + r;
                C[(size_t)rowg * N + col] = (f16)(acc[mt][nt][r] + bv);
            }
        }
}

// ---------------------------------------------------------------------------
__device__ __forceinline__ void gload_lds16(const void* g, void* l) {
    __builtin_amdgcn_global_load_lds((const __attribute__((address_space(1))) void*)g,
                                     (__attribute__((address_space(3))) void*)l, 16, 0, 0);
}

// Device-coherent 4B store: write-through past L1/L2 to the coherence point
// (MALL). Visible device-wide once vmcnt retires - no wbl2 fence needed.
__device__ __forceinline__ void gst_cc(void* p, unsigned v) {
    asm volatile("global_store_dword %0, %1, off sc0 sc1" :: "v"(p), "v"(v) : "memory");
}

__device__ __forceinline__ float f16lo(unsigned u) {
    return (float)__builtin_bit_cast(f16, (unsigned short)(u & 0xffffu));
}
__device__ __forceinline__ float f16hi(unsigned u) {
    return (float)__builtin_bit_cast(f16, (unsigned short)(u >> 16));
}

__device__ __forceinline__ unsigned aload(unsigned* p) {
    return __hip_atomic_load(p, __ATOMIC_RELAXED, __HIP_MEMORY_SCOPE_AGENT);
}

// Grid barrier v2: NO release fence (h is written write-through + vmcnt(0)
// drained before arrival), acquire side is buffer_inv only. Root serial-RMW
// chain replaced by parallel leader-poll of all 8 group arrival lines.
// Monotonic generation counters (survive the 2-launch split).
//   bar[g*32]     : group-g arrival count   (groups = wg%8 ~ per-XCD)
//   bar[(8+g)*32] : group-g release count
__device__ __forceinline__ void grid_sync(unsigned* bar, int wg) {
    asm volatile("s_waitcnt vmcnt(0)" ::: "memory");   // h stores at MALL
    __syncthreads();
    if (threadIdx.x == 0) {
        const int g = wg & (NGRP - 1);
        unsigned* arr = bar + g * 32;
        unsigned* rel = bar + (8 + g) * 32;
        unsigned a   = atomicAdd(arr, 1u);
        unsigned gen = a / (unsigned)GSZ;
        if (a % (unsigned)GSZ == (unsigned)(GSZ - 1)) {   // group leader this gen
            const unsigned tgt = (gen + 1u) * (unsigned)GSZ;
            for (;;) {
                unsigned v0 = aload(bar + 0 * 32), v1 = aload(bar + 1 * 32);
                unsigned v2 = aload(bar + 2 * 32), v3 = aload(bar + 3 * 32);
                unsigned v4 = aload(bar + 4 * 32), v5 = aload(bar + 5 * 32);
                unsigned v6 = aload(bar + 6 * 32), v7 = aload(bar + 7 * 32);
                unsigned mn = min(min(min(v0, v1), min(v2, v3)),
                                  min(min(v4, v5), min(v6, v7)));
                if (mn >= tgt) break;
                __builtin_amdgcn_s_sleep(2);
            }
            atomicAdd(rel, 1u);
        }
        while (aload(rel) < gen + 1u) __builtin_amdgcn_s_sleep(2);
        __builtin_amdgcn_fence(__ATOMIC_ACQUIRE, "agent");   // buffer_inv only
    }
    __syncthreads();
}

__device__ __forceinline__ float sigm(float v) { return 1.f / (1.f + __expf(-v)); }

// ---------------------------------------------------------------------------
// Persistent fused 2-layer LSTM scan. Iteration i: L0 computes step i (i<256),
// L1 computes step i-1 (i>=1). Weights held in registers for the whole launch.
//
// R7 == R6 resubmission (R6 bench died at container level, no kernel verdict):
// cross-XCD h handoff without release fences. h stores are packed 32-bit
// sc0/sc1 write-through stores; grid barrier does no wbl2 (out/c dirty lines
// flush lazily at kernel end) and only a buffer_inv on the acquire side.
// Compute/staging structure identical to R5 (verified).
__global__ __launch_bounds__(512, 2) __attribute__((amdgpu_waves_per_eu(2, 2)))
void scan_kernel(
    const f16* __restrict__ gx0,    // gates0 chunk base [nt][128][4096]
    int t_begin, int t_end,
    const f16* __restrict__ wih1, const f16* __restrict__ whh0,
    const f16* __restrict__ whh1, const float* __restrict__ bias1,
    f16* __restrict__ h0a, f16* __restrict__ h0b,
    f16* __restrict__ h1a, f16* __restrict__ h1b,
    float* __restrict__ c0, float* __restrict__ c1,
    float* __restrict__ out, unsigned* __restrict__ bar)
{
    __shared__ __align__(1024) char smem[131072];
    float* ep = (float*)smem;

    const int tid  = threadIdx.x;
    const int wg   = blockIdx.x;
    const int lane = tid & 63;
    const int w    = tid >> 6;
    const int lrow = lane & 15, koff = lane >> 4;
    const unsigned swz   = (unsigned)((lane & 7) << 4);
    const unsigned e0s   = ((unsigned)(koff * 16)) ^ swz;         // (kc&1)==0
    const unsigned e1s   = ((unsigned)(64 + koff * 16)) ^ swz;    // (kc&1)==1
    const unsigned lane16 = (unsigned)(lane << 4);

    if (wg < 64) {
        // ---------------- Layer 0: rowg(2) x ug(32 units), waves np(4) x kh(2)
        const int rowg = wg >> 5, ug = wg & 31;
        const int np = w & 3, kh = w >> 2;
        const int u0 = ug * 32;
        const size_t growb = (size_t)rowg * 64;
        const int cw = np * 32 + lrow;         // + nt*16

        half8 wreg[16][2];
        #pragma unroll
        for (int kc = 0; kc < 16; ++kc)
            #pragma unroll
            for (int nt = 0; nt < 2; ++nt) {
                int c = cw + nt * 16;
                wreg[kc][nt] = *(const half8*)(whh0
                    + (size_t)((c >> 5) * Hh + u0 + (c & 31)) * Hh
                    + kh * 512 + kc * 32 + koff * 8);
            }

        float creg[2][2];
        #pragma unroll
        for (int q = 0; q < 2; ++q) {
            int p = tid + q * 512, row = p >> 4, up = p & 15;
            float2 cc = *(const float2*)&c0[(growb + row) * Hh + u0 + 2 * up];
            creg[q][0] = cc.x; creg[q][1] = cc.y;
        }

        for (int i = t_begin; i < t_end; ++i) {
            if (i < 256) {
                const f16* hp = (i & 1) ? h0a : h0b;   // h0[i-1]
                f16*       hw = (i & 1) ? h0b : h0a;   // h0[i]
                const f16* gx = gx0 + (size_t)(i - t_begin) * (Bb * FourH);
                const char* hb = (const char*)hp + growb * 2048;

                // gate-input prefetch, 2 f16 packed per gate (plain cached loads)
                unsigned gxu[2][4];
                #pragma unroll
                for (int q = 0; q < 2; ++q) {
                    int p = tid + q * 512, row = p >> 4, up = p & 15;
                    const unsigned* gr = (const unsigned*)(gx + (growb + row) * FourH + u0) + up;
                    gxu[q][0] = gr[0];
                    gxu[q][1] = gr[512];
                    gxu[q][2] = gr[1024];
                    gxu[q][3] = gr[1536];
                }

                // single-shot stage: 64 rows x 2048 B (16 instr/wave)
                #pragma unroll
                for (int t = 0; t < 16; ++t) {
                    int row  = w * 8 + (t >> 1);
                    int half = t & 1;
                    gload_lds16(hb + (size_t)row * 2048 + half * 1024
                                   + (lane16 ^ ((unsigned)((row & 7) << 4))),
                                smem + row * 2048 + half * 1024);
                }

                asm volatile("s_waitcnt vmcnt(0)" ::: "memory");
                __syncthreads();

                f32x4 acc[4][2] = {};
                #pragma unroll
                for (int kc = 0; kc < 16; ++kc) {
                    unsigned off = (unsigned)(kh * 1024 + (kc >> 1) * 128)
                                 + ((kc & 1) ? e1s : e0s);
                    half8 a[4];
                    #pragma unroll
                    for (int mt = 0; mt < 4; ++mt)
                        a[mt] = *(const half8*)(smem + (mt * 16 + lrow) * 2048 + off);
                    #pragma unroll
                    for (int mt = 0; mt < 4; ++mt) {
                        acc[mt][0] = __builtin_amdgcn_mfma_f32_16x16x32_f16(a[mt], wreg[kc][0], acc[mt][0], 0, 0, 0);
                        acc[mt][1] = __builtin_amdgcn_mfma_f32_16x16x32_f16(a[mt], wreg[kc][1], acc[mt][1], 0, 0, 0);
                    }
                }
                __syncthreads();           // staging reads done before ep overwrite
                // ep[kh][row][c] : [2][64][128]
                #pragma unroll
                for (int mt = 0; mt < 4; ++mt)
                    #pragma unroll
                    for (int nt = 0; nt < 2; ++nt) {
                        int c = cw + nt * 16;
                        int rowb = mt * 16 + koff * 4;
                        #pragma unroll
                        for (int r = 0; r < 4; ++r)
                            ep[(kh * 64 + rowb + r) * 128 + c] = acc[mt][nt][r];
                    }
                __syncthreads();
                #pragma unroll
                for (int q = 0; q < 2; ++q) {
                    int p = tid + q * 512, row = p >> 4, up = p & 15, uu = 2 * up;
                    float2 iP = *(const float2*)&ep[row * 128 + uu];
                    float2 iQ = *(const float2*)&ep[(64 + row) * 128 + uu];
                    float2 fP = *(const float2*)&ep[row * 128 + 32 + uu];
                    float2 fQ = *(const float2*)&ep[(64 + row) * 128 + 32 + uu];
                    float2 gP = *(const float2*)&ep[row * 128 + 64 + uu];
                    float2 gQ = *(const float2*)&ep[(64 + row) * 128 + 64 + uu];
                    float2 oP = *(const float2*)&ep[row * 128 + 96 + uu];
                    float2 oQ = *(const float2*)&ep[(64 + row) * 128 + 96 + uu];
                    float ip0 = iP.x + iQ.x + f16lo(gxu[q][0]);
                    float ip1 = iP.y + iQ.y + f16hi(gxu[q][0]);
                    float fp0 = fP.x + fQ.x + f16lo(gxu[q][1]);
                    float fp1 = fP.y + fQ.y + f16hi(gxu[q][1]);
                    float gp0 = gP.x + gQ.x + f16lo(gxu[q][2]);
                    float gp1 = gP.y + gQ.y + f16hi(gxu[q][2]);
                    float op0 = oP.x + oQ.x + f16lo(gxu[q][3]);
                    float op1 = oP.y + oQ.y + f16hi(gxu[q][3]);
                    float cn0 = sigm(fp0) * creg[q][0] + sigm(ip0) * tanhf(gp0);
                    float cn1 = sigm(fp1) * creg[q][1] + sigm(ip1) * tanhf(gp1);
                    creg[q][0] = cn0; creg[q][1] = cn1;
                    f16 hA = (f16)(sigm(op0) * tanhf(cn0));
                    f16 hB = (f16)(sigm(op1) * tanhf(cn1));
                    unsigned hv = (unsigned)__builtin_bit_cast(unsigned short, hA)
                                | ((unsigned)__builtin_bit_cast(unsigned short, hB) << 16);
                    gst_cc((void*)(hw + (growb + row) * Hh + u0 + uu), hv);
                }
            }
            grid_sync(bar, wg);
        }
        #pragma unroll
        for (int q = 0; q < 2; ++q) {
            int p = tid + q * 512, row = p >> 4, up = p & 15;
            *(float2*)&c0[(growb + row) * Hh + u0 + 2 * up] = make_float2(creg[q][0], creg[q][1]);
        }
    } else {
        // ---------------- Layer 1: rowg(2) x ug(64; 16 units), waves = pure kq(8)
        const int wgl = wg - 64;
        const int rowg = wgl >> 6, ug = wgl & 63;
        const int kq = w;                      // 0..7 : K-window kq*256 of 2048
        const int u0 = ug * 16;
        const size_t growb = (size_t)rowg * 64;
        const int l7 = lane & 7;

        const f16* wbase = (kq < 4) ? wih1 : whh1;
        half8 wreg[8][4];                      // [kc][nt], K = (kq&3)*256 + kc*32
        #pragma unroll
        for (int kc = 0; kc < 8; ++kc)
            #pragma unroll
            for (int nt = 0; nt < 4; ++nt)     // col = nt*16+lrow: gate=nt, unit=lrow
                wreg[kc][nt] = *(const half8*)(wbase
                    + (size_t)(nt * Hh + u0 + lrow) * Hh
                    + (kq & 3) * 256 + kc * 32 + koff * 8);

        const int erow = tid >> 3, eup = tid & 7, euu = 2 * eup;
        float crg0, crg1;
        { float2 cc = *(const float2*)&c1[(growb + erow) * Hh + u0 + euu];
          crg0 = cc.x; crg1 = cc.y; }
        float2 bI = *(const float2*)&bias1[u0 + euu];
        float2 bF = *(const float2*)&bias1[Hh + u0 + euu];
        float2 bG = *(const float2*)&bias1[2 * Hh + u0 + euu];
        float2 bO = *(const float2*)&bias1[3 * Hh + u0 + euu];

        const unsigned wb = (unsigned)kq * 16384u;   // this wave's 16 KB LDS slab
        const int r2 = lane >> 5;                    // 0/1 (row parity per instr)
        const int chs0 = lane & 31;                  // 16B-chunk slot in 512B row

        #define STG(rb_, bo_) { \
            _Pragma("unroll") \
            for (int t = 0; t < 8; ++t) { \
                int rl = (rb_) + t * 2 + r2; \
                gload_lds16(src + (size_t)rl * 2048 \
                                + ((unsigned)((chs0 ^ (rl & 7)) << 4)), \
                            smem + wb + (bo_) + (unsigned)(t * 1024)); \
            } }
        #define CMT(mt_, bo_) { \
            _Pragma("unroll") \
            for (int kc = 0; kc < 8; ++kc) { \
                half8 a = *(const half8*)(smem + wb + (bo_) \
                            + (unsigned)(lrow * 512) \
                            + ((unsigned)(((kc * 4 + koff) ^ l7) << 4))); \
                acc[mt_][0] = __builtin_amdgcn_mfma_f32_16x16x32_f16(a, wreg[kc][0], acc[mt_][0], 0, 0, 0); \
                acc[mt_][1] = __builtin_amdgcn_mfma_f32_16x16x32_f16(a, wreg[kc][1], acc[mt_][1], 0, 0, 0); \
                acc[mt_][2] = __builtin_amdgcn_mfma_f32_16x16x32_f16(a, wreg[kc][2], acc[mt_][2], 0, 0, 0); \
                acc[mt_][3] = __builtin_amdgcn_mfma_f32_16x16x32_f16(a, wreg[kc][3], acc[mt_][3], 0, 0, 0); \
            } }

        for (int i = t_begin; i < t_end; ++i) {
            int t1 = i - 1;
            if (t1 >= 0) {
                const f16* a0 = (t1 & 1) ? h0b : h0a;  // h0[t1]
                const f16* a1 = (t1 & 1) ? h1a : h1b;  // h1[t1-1]
                f16*       hw = (t1 & 1) ? h1b : h1a;  // h1[t1]
                const char* src = ((kq < 4) ? (const char*)a0 : (const char*)a1)
                                + growb * 2048 + (size_t)(kq & 3) * 512;

                f32x4 acc[4][4] = {};
                STG(0, 0u)
                STG(16, 8192u)
                asm volatile("s_waitcnt vmcnt(8)" ::: "memory");   // rows 0-15 in
                CMT(0, 0u)
                asm volatile("s_waitcnt lgkmcnt(0)" ::: "memory"); // buf0 reads done
                STG(32, 0u)
                asm volatile("s_waitcnt vmcnt(8)" ::: "memory");   // rows 16-31 in
                CMT(1, 8192u)
                asm volatile("s_waitcnt lgkmcnt(0)" ::: "memory"); // buf1 reads done
                STG(48, 8192u)
                asm volatile("s_waitcnt vmcnt(8)" ::: "memory");   // rows 32-47 in
                CMT(2, 0u)
                asm volatile("s_waitcnt vmcnt(0)" ::: "memory");   // rows 48-63 in
                CMT(3, 8192u)

                // ep partials into OWN slab (64 rows x 64 cols f32 = 16 KB).
                // layout: slab[row*256 + (c ^ (sw<<4))*4], sw=(row^(row>>2))&3
                #pragma unroll
                for (int mt = 0; mt < 4; ++mt)
                    #pragma unroll
                    for (int nt = 0; nt < 4; ++nt) {
                        int c = nt * 16 + lrow;
                        #pragma unroll
                        for (int r = 0; r < 4; ++r) {
                            int row = mt * 16 + koff * 4 + r;
                            int sw  = (row ^ (row >> 2)) & 3;
                            *(float*)(smem + wb + (unsigned)(row * 256)
                                      + (unsigned)((c ^ (sw << 4)) * 4)) = acc[mt][nt][r];
                        }
                    }
                __syncthreads();
                {
                    int sw = (erow ^ (erow >> 2)) & 3;
                    const char* rbase = smem + (unsigned)(erow * 256);
                    float s0x = bI.x, s0y = bI.y, s1x = bF.x, s1y = bF.y;
                    float s2x = bG.x, s2y = bG.y, s3x = bO.x, s3y = bO.y;
                    #pragma unroll
                    for (int k8 = 0; k8 < 8; ++k8) {
                        const char* base = rbase + (unsigned)k8 * 16384u;
                        float2 v0 = *(const float2*)(base + (unsigned)((( 0 + euu) ^ (sw << 4)) * 4));
                        float2 v1 = *(const float2*)(base + (unsigned)(((16 + euu) ^ (sw << 4)) * 4));
                        float2 v2 = *(const float2*)(base + (unsigned)(((32 + euu) ^ (sw << 4)) * 4));
                        float2 v3 = *(const float2*)(base + (unsigned)(((48 + euu) ^ (sw << 4)) * 4));
                        s0x += v0.x; s0y += v0.y; s1x += v1.x; s1y += v1.y;
                        s2x += v2.x; s2y += v2.y; s3x += v3.x; s3y += v3.y;
                    }
                    float cn0 = sigm(s1x) * crg0 + sigm(s0x) * tanhf(s2x); crg0 = cn0;
                    float cn1 = sigm(s1y) * crg1 + sigm(s0y) * tanhf(s2y); crg1 = cn1;
                    float hn0 = sigm(s3x) * tanhf(cn0);
                    float hn1 = sigm(s3y) * tanhf(cn1);
                    unsigned hv = (unsigned)__builtin_bit_cast(unsigned short, (f16)hn0)
                                | ((unsigned)__builtin_bit_cast(unsigned short, (f16)hn1) << 16);
                    gst_cc((void*)(hw + (growb + erow) * Hh + u0 + euu), hv);
                    *(float2*)&out[(growb + erow) * (size_t)(Ss * Hh)
                                   + (size_t)t1 * Hh + u0 + euu] = make_float2(hn0, hn1);
                }
            }
            grid_sync(bar, wg);
        }
        *(float2*)&c1[(growb + erow) * Hh + u0 + euu] = make_float2(crg0, crg1);
        #undef STG
        #undef CMT
    }
}

// ---------------------------------------------------------------------------
extern "C" void kernel_launch(void* const* d_in, const int* in_sizes, int n_in,
                              void* d_out, int out_size, void* d_ws, size_t ws_size,
                              hipStream_t stream) {
    const int*   x      = (const int*)  d_in[0];
    const float* emb    = (const float*)d_in[1];
    const float* proj_w = (const float*)d_in[2];
    const float* proj_b = (const float*)d_in[3];
    const float* W_ih0  = (const float*)d_in[4];
    const float* W_hh0  = (const float*)d_in[5];
    const float* b_ih0  = (const float*)d_in[6];
    const float* b_hh0  = (const float*)d_in[7];
    const float* W_ih1  = (const float*)d_in[8];
    const float* W_hh1  = (const float*)d_in[9];
    const float* b_ih1  = (const float*)d_in[10];
    const float* b_hh1  = (const float*)d_in[11];
    float* out = (float*)d_out;

    char* ws = (char*)d_ws;
    f16* emb_sum = (f16*)(ws);                               // 32 MB [S,B,E]
    f16* x_in    = (f16*)(ws + 33554432ull);                 // 32 MB [S,B,E]
    f16* gates   = (f16*)(ws + 67108864ull);                 // 128 MB (128-step chunk)
    char* wp     = ws + 201326592ull;
    f16* pw_f   = (f16*)wp; wp += (size_t)Ee * Ee * 2;
    f16* wih0_f = (f16*)wp; wp += (size_t)FourH * Ee * 2;
    f16* whh0_f = (f16*)wp; wp += (size_t)FourH * Hh * 2;
    f16* wih1_f = (f16*)wp; wp += (size_t)FourH * Hh * 2;
    f16* whh1_f = (f16*)wp; wp += (size_t)FourH * Hh * 2;
    float* bias0 = (float*)wp; wp += FourH * 4;
    float* bias1 = (float*)wp; wp += FourH * 4;
    char* zbase = wp;
    f16*   h0a = (f16*)wp;   wp += (size_t)Bb * Hh * 2;
    f16*   h0b = (f16*)wp;   wp += (size_t)Bb * Hh * 2;
    f16*   h1a = (f16*)wp;   wp += (size_t)Bb * Hh * 2;
    f16*   h1b = (f16*)wp;   wp += (size_t)Bb * Hh * 2;
    float* c0  = (float*)wp; wp += (size_t)Bb * Hh * 4;
    float* c1  = (float*)wp; wp += (size_t)Bb * Hh * 4;
    unsigned* bar = (unsigned*)wp; wp += 4096;               // barrier counters
    size_t zbytes = (size_t)(wp - zbase);

    // Prologue: converts, biases, zero state+barrier
    cvt_f16_kernel<<<512, 256, 0, stream>>>(proj_w, pw_f,   Ee * Ee);
    cvt_f16_kernel<<<512, 256, 0, stream>>>(W_ih0,  wih0_f, FourH * Ee);
    cvt_f16_kernel<<<512, 256, 0, stream>>>(W_hh0,  whh0_f, FourH * Hh);
    cvt_f16_kernel<<<512, 256, 0, stream>>>(W_ih1,  wih1_f, FourH * Hh);
    cvt_f16_kernel<<<512, 256, 0, stream>>>(W_hh1,  whh1_f, FourH * Hh);
    bias_combine_kernel<<<32, 256, 0, stream>>>(b_ih0, b_hh0, b_ih1, b_hh1, bias0, bias1);
    hipMemsetAsync(zbase, 0, zbytes, stream);

    // Embedding + input projection (time-major)
    emb_kernel<<<Mrows, 256, 0, stream>>>(x, emb, emb_sum);
    gemm_bt_kernel<<<dim3(Ee / BN, Mrows / BM), 256, 0, stream>>>(
        emb_sum, pw_f, proj_b, x_in, Mrows, Ee, Ee);

    // Two half-sequence passes: gates0 GEMM chunk + cooperative scan
    const int CM = Mrows / 2;   // 16384 rows = 128 steps

    for (int half = 0; half < 2; ++half) {
        gemm_bt_kernel<<<dim3(FourH / BN, CM / BM), 256, 0, stream>>>(
            x_in + (size_t)half * CM * Ee, wih0_f, bias0, gates, CM, FourH, Ee);
        int tb = half * 128;
        int te = (half == 0) ? 128 : 257;   // second pass runs one extra L1-only iter
        const f16* gxp = gates;
        void* args[] = { (void*)&gxp, (void*)&tb, (void*)&te,
                         (void*)&wih1_f, (void*)&whh0_f, (void*)&whh1_f, (void*)&bias1,
                         (void*)&h0a, (void*)&h0b, (void*)&h1a, (void*)&h1b,
                         (void*)&c0, (void*)&c1, (void*)&out, (void*)&bar };
        hipLaunchCooperativeKernel((const void*)scan_kernel, dim3(NBLK), dim3(512),
                                   args, 0, stream);
    }
}

// Round 8
// 2997.782 us; speedup vs baseline: 1.6321x; 1.0404x over previous
//
#include <hip/hip_runtime.h>
#include <hip/hip_bf16.h>

#define Bb    128
#define Ss    256
#define Ff    4
#define Vv    1024
#define Ee    512
#define Hh    1024
#define FourH 4096
#define Mrows (Bb * Ss)
#define NBLK  192      // 64 layer-0 WGs + 128 layer-1 WGs

typedef _Float16 f16;
typedef __attribute__((ext_vector_type(8))) _Float16 half8;
typedef __attribute__((ext_vector_type(4))) float f32x4;

// ---------------------------------------------------------------------------
__global__ void cvt_f16_kernel(const float* __restrict__ s, f16* __restrict__ d, int n) {
    int i = blockIdx.x * blockDim.x + threadIdx.x;
    int stride = gridDim.x * blockDim.x;
    for (; i < n; i += stride) d[i] = (f16)s[i];
}

__global__ void bias_combine_kernel(const float* __restrict__ a, const float* __restrict__ b,
                                    const float* __restrict__ c, const float* __restrict__ d,
                                    float* __restrict__ o0, float* __restrict__ o1) {
    int i = blockIdx.x * blockDim.x + threadIdx.x;
    if (i < FourH) o0[i] = a[i] + b[i];
    else if (i < 2 * FourH) { int j = i - FourH; o1[j] = c[j] + d[j]; }
}

// Embedding: sum over F tables -> f16 [S, B, E] (time-major)
__global__ void emb_kernel(const int* __restrict__ x, const float* __restrict__ emb,
                           f16* __restrict__ out) {
    int r = blockIdx.x;
    int t = threadIdx.x;
    int b = r / Ss, s = r % Ss;
    const int* xr = x + (size_t)r * Ff;
    const float* e0 = emb + (size_t)xr[0] * Ee;
    const float* e1 = emb + (size_t)(Vv + xr[1]) * Ee;
    const float* e2 = emb + (size_t)(2 * Vv + xr[2]) * Ee;
    const float* e3 = emb + (size_t)(3 * Vv + xr[3]) * Ee;
    f16* orow = out + (size_t)(s * Bb + b) * Ee;
    for (int e = t; e < Ee; e += 256) orow[e] = (f16)(e0[e] + e1[e] + e2[e] + e3[e]);
}

// ---------------------------------------------------------------------------
// C[M,N] = A[M,K] @ B[N,K]^T + bias[N]  (f16 in, f16 out, fp32 accum)
#define BM 128
#define BN 128
#define BK 32
#define LDP 40

__global__ __launch_bounds__(256) void gemm_bt_kernel(
    const f16* __restrict__ A, const f16* __restrict__ Bw,
    const float* __restrict__ bias, f16* __restrict__ C,
    int M, int N, int K)
{
    __shared__ f16 As[BM * LDP];
    __shared__ f16 Bs[BN * LDP];
    int tid  = threadIdx.x;
    int n0   = blockIdx.x * BN;
    int m0   = blockIdx.y * BM;
    int w    = tid >> 6, lane = tid & 63;
    int wm   = (w >> 1) * 64, wn = (w & 1) * 64;
    int lrow = lane & 15, koff = lane >> 4;

    f32x4 acc[4][4] = {};

    for (int kb = 0; kb < K; kb += BK) {
        __syncthreads();
        #pragma unroll
        for (int h = 0; h < 2; ++h) {
            int ch  = tid + h * 256;
            int row = ch >> 2;
            int cc  = (ch & 3) * 8;
            *reinterpret_cast<uint4*>(&As[row * LDP + cc]) =
                *reinterpret_cast<const uint4*>(A + (size_t)(m0 + row) * K + kb + cc);
            *reinterpret_cast<uint4*>(&Bs[row * LDP + cc]) =
                *reinterpret_cast<const uint4*>(Bw + (size_t)(n0 + row) * K + kb + cc);
        }
        __syncthreads();
        half8 af[4], bf[4];
        #pragma unroll
        for (int mt = 0; mt < 4; ++mt)
            af[mt] = *reinterpret_cast<const half8*>(&As[(wm + mt * 16 + lrow) * LDP + koff * 8]);
        #pragma unroll
        for (int nt = 0; nt < 4; ++nt)
            bf[nt] = *reinterpret_cast<const half8*>(&Bs[(wn + nt * 16 + lrow) * LDP + koff * 8]);
        #pragma unroll
        for (int mt = 0; mt < 4; ++mt)
            #pragma unroll
            for (int nt = 0; nt < 4; ++nt)
                acc[mt][nt] = __builtin_amdgcn_mfma_f32_16x16x32_f16(af[mt], bf[nt], acc[mt][nt], 0, 0, 0);
    }

    #pragma unroll
    for (int mt = 0; mt < 4; ++mt)
        #pragma unroll
        for (int nt = 0; nt < 4; ++nt) {
            int col = n0 + wn + nt * 16 + lrow;
            float bv = bias[col];
            #pragma unroll
            for (int r = 0; r < 4; ++r) {
                int rowg = m0 + wm + mt * 16 + koff * 4 + r;
                C[(size_t)rowg * N + col] = (f16)(acc[mt][nt][r] + bv);
            }
        }
}

// ---------------------------------------------------------------------------
__device__ __forceinline__ void gload_lds16(const void* g, void* l) {
    __builtin_amdgcn_global_load_lds((const __attribute__((address_space(1))) void*)g,
                                     (__attribute__((address_space(3))) void*)l, 16, 0, 0);
}

// Device-coherent 4B store: write-through past L1/L2 to the coherence point
// (MALL). Visible device-wide once vmcnt retires - no wbl2 fence needed.
__device__ __forceinline__ void gst_cc(void* p, unsigned v) {
    asm volatile("global_store_dword %0, %1, off sc0 sc1" :: "v"(p), "v"(v) : "memory");
}

__device__ __forceinline__ float f16lo(unsigned u) {
    return (float)__builtin_bit_cast(f16, (unsigned short)(u & 0xffffu));
}
__device__ __forceinline__ float f16hi(unsigned u) {
    return (float)__builtin_bit_cast(f16, (unsigned short)(u >> 16));
}

__device__ __forceinline__ unsigned aload(unsigned* p) {
    return __hip_atomic_load(p, __ATOMIC_RELAXED, __HIP_MEMORY_SCOPE_AGENT);
}

__device__ __forceinline__ float sigm(float v) { return 1.f / (1.f + __expf(-v)); }

// ---------------------------------------------------------------------------
// Persistent fused 2-layer LSTM scan, R8: DECOUPLED PRODUCER-CONSUMER SYNC.
// The grid splits into 2 independent halves (rowg). Per half:
//  * L0 group (32 WGs): internal monotonic barrier per step; its release
//    counter rel0 == L0_done (completed steps), published device-wide.
//  * L1 group (64 WGs): internal barrier (rel1 == L1_done); before staging,
//    gates on rel0 >= i (h0[i-1] at MALL) then acquire-inv (AFTER the gate -
//    placement kills the stale-L2-refill race).
//  * h0 is a 4-deep ring: L0 may run up to 3 steps ahead of L1; WAR gate
//    rel1 >= i-2 sits after L0's MFMA phase (overlapped, no fence).
// h handoff mechanism from R7 (verified): packed sc0/sc1 write-through
// stores + vmcnt(0) drain before barrier arrival. No global barrier at all.
__global__ __launch_bounds__(512, 2) __attribute__((amdgpu_waves_per_eu(2, 2)))
void scan_kernel(
    const f16* __restrict__ gx0,    // gates0 chunk base [nt][128][4096]
    int t_begin, int t_end,
    const f16* __restrict__ wih1, const f16* __restrict__ whh0,
    const f16* __restrict__ whh1, const float* __restrict__ bias1,
    f16* __restrict__ h0r,          // 4-slot ring [4][128][1024]
    f16* __restrict__ h1a, f16* __restrict__ h1b,
    float* __restrict__ c0, float* __restrict__ c1,
    float* __restrict__ out, unsigned* __restrict__ bar)
{
    __shared__ __align__(1024) char smem[131072];
    float* ep = (float*)smem;

    const int tid  = threadIdx.x;
    const int wg   = blockIdx.x;
    const int lane = tid & 63;
    const int w    = tid >> 6;
    const int lrow = lane & 15, koff = lane >> 4;
    const unsigned swz   = (unsigned)((lane & 7) << 4);
    const unsigned e0s   = ((unsigned)(koff * 16)) ^ swz;         // (kc&1)==0
    const unsigned e1s   = ((unsigned)(64 + koff * 16)) ^ swz;    // (kc&1)==1
    const unsigned lane16 = (unsigned)(lane << 4);
    const size_t HSLOT = (size_t)Bb * Hh;   // f16 elems per h0 ring slot

    if (wg < 64) {
        // ---------------- Layer 0: rowg(2) x ug(32 units), waves np(4) x kh(2)
        const int rowg = wg >> 5, ug = wg & 31;
        const int np = w & 3, kh = w >> 2;
        const int u0 = ug * 32;
        const size_t growb = (size_t)rowg * 64;
        const int cw = np * 32 + lrow;         // + nt*16

        unsigned* arr0 = bar + (0 + rowg) * 32;   // L0 arrivals (this half)
        unsigned* rel0 = bar + (2 + rowg) * 32;   // L0 release == L0_done
        unsigned* rel1 = bar + (6 + rowg) * 32;   // L1_done (read-only here)

        half8 wreg[16][2];
        #pragma unroll
        for (int kc = 0; kc < 16; ++kc)
            #pragma unroll
            for (int nt = 0; nt < 2; ++nt) {
                int c = cw + nt * 16;
                wreg[kc][nt] = *(const half8*)(whh0
                    + (size_t)((c >> 5) * Hh + u0 + (c & 31)) * Hh
                    + kh * 512 + kc * 32 + koff * 8);
            }

        float creg[2][2];
        #pragma unroll
        for (int q = 0; q < 2; ++q) {
            int p = tid + q * 512, row = p >> 4, up = p & 15;
            float2 cc = *(const float2*)&c0[(growb + row) * Hh + u0 + 2 * up];
            creg[q][0] = cc.x; creg[q][1] = cc.y;
        }

        for (int i = t_begin; i < t_end; ++i) {
            if (i < 256) {
                const f16* hp = h0r + (size_t)((unsigned)((i - 1) & 3)) * HSLOT; // h0[i-1]
                f16*       hw = h0r + (size_t)(i & 3) * HSLOT;                   // h0[i]
                const f16* gx = gx0 + (size_t)(i - t_begin) * (Bb * FourH);
                const char* hb = (const char*)hp + growb * 2048;

                // gate-input prefetch, 2 f16 packed per gate (plain cached loads)
                unsigned gxu[2][4];
                #pragma unroll
                for (int q = 0; q < 2; ++q) {
                    int p = tid + q * 512, row = p >> 4, up = p & 15;
                    const unsigned* gr = (const unsigned*)(gx + (growb + row) * FourH + u0) + up;
                    gxu[q][0] = gr[0];
                    gxu[q][1] = gr[512];
                    gxu[q][2] = gr[1024];
                    gxu[q][3] = gr[1536];
                }

                // single-shot stage: 64 rows x 2048 B (16 instr/wave)
                #pragma unroll
                for (int t = 0; t < 16; ++t) {
                    int row  = w * 8 + (t >> 1);
                    int half = t & 1;
                    gload_lds16(hb + (size_t)row * 2048 + half * 1024
                                   + (lane16 ^ ((unsigned)((row & 7) << 4))),
                                smem + row * 2048 + half * 1024);
                }

                asm volatile("s_waitcnt vmcnt(0)" ::: "memory");
                __syncthreads();

                f32x4 acc[4][2] = {};
                #pragma unroll
                for (int kc = 0; kc < 16; ++kc) {
                    unsigned off = (unsigned)(kh * 1024 + (kc >> 1) * 128)
                                 + ((kc & 1) ? e1s : e0s);
                    half8 a[4];
                    #pragma unroll
                    for (int mt = 0; mt < 4; ++mt)
                        a[mt] = *(const half8*)(smem + (mt * 16 + lrow) * 2048 + off);
                    #pragma unroll
                    for (int mt = 0; mt < 4; ++mt) {
                        acc[mt][0] = __builtin_amdgcn_mfma_f32_16x16x32_f16(a[mt], wreg[kc][0], acc[mt][0], 0, 0, 0);
                        acc[mt][1] = __builtin_amdgcn_mfma_f32_16x16x32_f16(a[mt], wreg[kc][1], acc[mt][1], 0, 0, 0);
                    }
                }
                __syncthreads();           // staging reads done before ep overwrite
                // ep[kh][row][c] : [2][64][128]
                #pragma unroll
                for (int mt = 0; mt < 4; ++mt)
                    #pragma unroll
                    for (int nt = 0; nt < 2; ++nt) {
                        int c = cw + nt * 16;
                        int rowb = mt * 16 + koff * 4;
                        #pragma unroll
                        for (int r = 0; r < 4; ++r)
                            ep[(kh * 64 + rowb + r) * 128 + c] = acc[mt][nt][r];
                    }
                // WAR gate on h0 ring slot i&3: L1 must have consumed h0[i-4]
                // (i.e. finished its iteration i-3 -> rel1 >= i-2). Overlapped
                // here (after MFMA); no fence needed for WAR.
                if (tid == 0) {
                    while ((int)aload(rel1) < i - 2) __builtin_amdgcn_s_sleep(2);
                }
                __syncthreads();
                #pragma unroll
                for (int q = 0; q < 2; ++q) {
                    int p = tid + q * 512, row = p >> 4, up = p & 15, uu = 2 * up;
                    float2 iP = *(const float2*)&ep[row * 128 + uu];
                    float2 iQ = *(const float2*)&ep[(64 + row) * 128 + uu];
                    float2 fP = *(const float2*)&ep[row * 128 + 32 + uu];
                    float2 fQ = *(const float2*)&ep[(64 + row) * 128 + 32 + uu];
                    float2 gP = *(const float2*)&ep[row * 128 + 64 + uu];
                    float2 gQ = *(const float2*)&ep[(64 + row) * 128 + 64 + uu];
                    float2 oP = *(const float2*)&ep[row * 128 + 96 + uu];
                    float2 oQ = *(const float2*)&ep[(64 + row) * 128 + 96 + uu];
                    float ip0 = iP.x + iQ.x + f16lo(gxu[q][0]);
                    float ip1 = iP.y + iQ.y + f16hi(gxu[q][0]);
                    float fp0 = fP.x + fQ.x + f16lo(gxu[q][1]);
                    float fp1 = fP.y + fQ.y + f16hi(gxu[q][1]);
                    float gp0 = gP.x + gQ.x + f16lo(gxu[q][2]);
                    float gp1 = gP.y + gQ.y + f16hi(gxu[q][2]);
                    float op0 = oP.x + oQ.x + f16lo(gxu[q][3]);
                    float op1 = oP.y + oQ.y + f16hi(gxu[q][3]);
                    float cn0 = sigm(fp0) * creg[q][0] + sigm(ip0) * tanhf(gp0);
                    float cn1 = sigm(fp1) * creg[q][1] + sigm(ip1) * tanhf(gp1);
                    creg[q][0] = cn0; creg[q][1] = cn1;
                    f16 hA = (f16)(sigm(op0) * tanhf(cn0));
                    f16 hB = (f16)(sigm(op1) * tanhf(cn1));
                    unsigned hv = (unsigned)__builtin_bit_cast(unsigned short, hA)
                                | ((unsigned)__builtin_bit_cast(unsigned short, hB) << 16);
                    gst_cc((void*)(hw + (growb + row) * Hh + u0 + uu), hv);
                }
            }
            // ---- L0 internal 32-WG barrier (rel0 doubles as L0_done) ----
            asm volatile("s_waitcnt vmcnt(0)" ::: "memory");   // h0 stores at MALL
            __syncthreads();
            if (tid == 0) {
                unsigned a = atomicAdd(arr0, 1u);
                unsigned gen = a >> 5;
                if ((a & 31u) == 31u) atomicAdd(rel0, 1u);
                while (aload(rel0) < gen + 1u) __builtin_amdgcn_s_sleep(2);
                __builtin_amdgcn_fence(__ATOMIC_ACQUIRE, "agent");   // inv for own h0 reads
            }
            __syncthreads();
        }
        #pragma unroll
        for (int q = 0; q < 2; ++q) {
            int p = tid + q * 512, row = p >> 4, up = p & 15;
            *(float2*)&c0[(growb + row) * Hh + u0 + 2 * up] = make_float2(creg[q][0], creg[q][1]);
        }
    } else {
        // ---------------- Layer 1: rowg(2) x ug(64; 16 units), waves = pure kq(8)
        const int wgl = wg - 64;
        const int rowg = wgl >> 6, ug = wgl & 63;
        const int kq = w;                      // 0..7 : K-window kq*256 of 2048
        const int u0 = ug * 16;
        const size_t growb = (size_t)rowg * 64;
        const int l7 = lane & 7;

        unsigned* arr1 = bar + (4 + rowg) * 32;   // L1 arrivals (this half)
        unsigned* rel1 = bar + (6 + rowg) * 32;   // L1 release == L1_done
        unsigned* rel0 = bar + (2 + rowg) * 32;   // L0_done (read-only here)

        const f16* wbase = (kq < 4) ? wih1 : whh1;
        half8 wreg[8][4];                      // [kc][nt], K = (kq&3)*256 + kc*32
        #pragma unroll
        for (int kc = 0; kc < 8; ++kc)
            #pragma unroll
            for (int nt = 0; nt < 4; ++nt)     // col = nt*16+lrow: gate=nt, unit=lrow
                wreg[kc][nt] = *(const half8*)(wbase
                    + (size_t)(nt * Hh + u0 + lrow) * Hh
                    + (kq & 3) * 256 + kc * 32 + koff * 8);

        const int erow = tid >> 3, eup = tid & 7, euu = 2 * eup;
        float crg0, crg1;
        { float2 cc = *(const float2*)&c1[(growb + erow) * Hh + u0 + euu];
          crg0 = cc.x; crg1 = cc.y; }
        float2 bI = *(const float2*)&bias1[u0 + euu];
        float2 bF = *(const float2*)&bias1[Hh + u0 + euu];
        float2 bG = *(const float2*)&bias1[2 * Hh + u0 + euu];
        float2 bO = *(const float2*)&bias1[3 * Hh + u0 + euu];

        const unsigned wb = (unsigned)kq * 16384u;   // this wave's 16 KB LDS slab
        const int r2 = lane >> 5;                    // 0/1 (row parity per instr)
        const int chs0 = lane & 31;                  // 16B-chunk slot in 512B row

        #define STG(rb_, bo_) { \
            _Pragma("unroll") \
            for (int t = 0; t < 8; ++t) { \
                int rl = (rb_) + t * 2 + r2; \
                gload_lds16(src + (size_t)rl * 2048 \
                                + ((unsigned)((chs0 ^ (rl & 7)) << 4)), \
                            smem + wb + (bo_) + (unsigned)(t * 1024)); \
            } }
        #define CMT(mt_, bo_) { \
            _Pragma("unroll") \
            for (int kc = 0; kc < 8; ++kc) { \
                half8 a = *(const half8*)(smem + wb + (bo_) \
                            + (unsigned)(lrow * 512) \
                            + ((unsigned)(((kc * 4 + koff) ^ l7) << 4))); \
                acc[mt_][0] = __builtin_amdgcn_mfma_f32_16x16x32_f16(a, wreg[kc][0], acc[mt_][0], 0, 0, 0); \
                acc[mt_][1] = __builtin_amdgcn_mfma_f32_16x16x32_f16(a, wreg[kc][1], acc[mt_][1], 0, 0, 0); \
                acc[mt_][2] = __builtin_amdgcn_mfma_f32_16x16x32_f16(a, wreg[kc][2], acc[mt_][2], 0, 0, 0); \
                acc[mt_][3] = __builtin_amdgcn_mfma_f32_16x16x32_f16(a, wreg[kc][3], acc[mt_][3], 0, 0, 0); \
            } }

        for (int i = t_begin; i < t_end; ++i) {
            int t1 = i - 1;
            if (t1 >= 0) {
                // Data gate: h0[t1] complete once rel0 >= i. Acquire-inv AFTER
                // the gate so no stale L2 refill can precede it.
                if (tid == 0) {
                    while ((int)aload(rel0) < i) __builtin_amdgcn_s_sleep(2);
                    __builtin_amdgcn_fence(__ATOMIC_ACQUIRE, "agent");
                }
                __syncthreads();

                const f16* a0 = h0r + (size_t)(t1 & 3) * HSLOT;  // h0[t1]
                const f16* a1 = (t1 & 1) ? h1a : h1b;            // h1[t1-1]
                f16*       hw = (t1 & 1) ? h1b : h1a;            // h1[t1]
                const char* src = ((kq < 4) ? (const char*)a0 : (const char*)a1)
                                + growb * 2048 + (size_t)(kq & 3) * 512;

                f32x4 acc[4][4] = {};
                STG(0, 0u)
                STG(16, 8192u)
                asm volatile("s_waitcnt vmcnt(8)" ::: "memory");   // rows 0-15 in
                CMT(0, 0u)
                asm volatile("s_waitcnt lgkmcnt(0)" ::: "memory"); // buf0 reads done
                STG(32, 0u)
                asm volatile("s_waitcnt vmcnt(8)" ::: "memory");   // rows 16-31 in
                CMT(1, 8192u)
                asm volatile("s_waitcnt lgkmcnt(0)" ::: "memory"); // buf1 reads done
                STG(48, 8192u)
                asm volatile("s_waitcnt vmcnt(8)" ::: "memory");   // rows 32-47 in
                CMT(2, 0u)
                asm volatile("s_waitcnt vmcnt(0)" ::: "memory");   // rows 48-63 in
                CMT(3, 8192u)

                // ep partials into OWN slab (64 rows x 64 cols f32 = 16 KB).
                // layout: slab[row*256 + (c ^ (sw<<4))*4], sw=(row^(row>>2))&3
                #pragma unroll
                for (int mt = 0; mt < 4; ++mt)
                    #pragma unroll
                    for (int nt = 0; nt < 4; ++nt) {
                        int c = nt * 16 + lrow;
                        #pragma unroll
                        for (int r = 0; r < 4; ++r) {
                            int row = mt * 16 + koff * 4 + r;
                            int sw  = (row ^ (row >> 2)) & 3;
                            *(float*)(smem + wb + (unsigned)(row * 256)
                                      + (unsigned)((c ^ (sw << 4)) * 4)) = acc[mt][nt][r];
                        }
                    }
                __syncthreads();
                {
                    int sw = (erow ^ (erow >> 2)) & 3;
                    const char* rbase = smem + (unsigned)(erow * 256);
                    float s0x = bI.x, s0y = bI.y, s1x = bF.x, s1y = bF.y;
                    float s2x = bG.x, s2y = bG.y, s3x = bO.x, s3y = bO.y;
                    #pragma unroll
                    for (int k8 = 0; k8 < 8; ++k8) {
                        const char* base = rbase + (unsigned)k8 * 16384u;
                        float2 v0 = *(const float2*)(base + (unsigned)((( 0 + euu) ^ (sw << 4)) * 4));
                        float2 v1 = *(const float2*)(base + (unsigned)(((16 + euu) ^ (sw << 4)) * 4));
                        float2 v2 = *(const float2*)(base + (unsigned)(((32 + euu) ^ (sw << 4)) * 4));
                        float2 v3 = *(const float2*)(base + (unsigned)(((48 + euu) ^ (sw << 4)) * 4));
                        s0x += v0.x; s0y += v0.y; s1x += v1.x; s1y += v1.y;
                        s2x += v2.x; s2y += v2.y; s3x += v3.x; s3y += v3.y;
                    }
                    float cn0 = sigm(s1x) * crg0 + sigm(s0x) * tanhf(s2x); crg0 = cn0;
                    float cn1 = sigm(s1y) * crg1 + sigm(s0y) * tanhf(s2y); crg1 = cn1;
                    float hn0 = sigm(s3x) * tanhf(cn0);
                    float hn1 = sigm(s3y) * tanhf(cn1);
                    unsigned hv = (unsigned)__builtin_bit_cast(unsigned short, (f16)hn0)
                                | ((unsigned)__builtin_bit_cast(unsigned short, (f16)hn1) << 16);
                    gst_cc((void*)(hw + (growb + erow) * Hh + u0 + euu), hv);
                    *(float2*)&out[(growb + erow) * (size_t)(Ss * Hh)
                                   + (size_t)t1 * Hh + u0 + euu] = make_float2(hn0, hn1);
                }
            }
            // ---- L1 internal 64-WG barrier (rel1 doubles as L1_done) ----
            asm volatile("s_waitcnt vmcnt(0)" ::: "memory");   // h1 stores at MALL
            __syncthreads();
            if (tid == 0) {
                unsigned a = atomicAdd(arr1, 1u);
                unsigned gen = a >> 6;
                if ((a & 63u) == 63u) atomicAdd(rel1, 1u);
                while (aload(rel1) < gen + 1u) __builtin_amdgcn_s_sleep(2);
            }
            __syncthreads();
        }
        *(float2*)&c1[(growb + erow) * Hh + u0 + euu] = make_float2(crg0, crg1);
        #undef STG
        #undef CMT
    }
}

// ---------------------------------------------------------------------------
extern "C" void kernel_launch(void* const* d_in, const int* in_sizes, int n_in,
                              void* d_out, int out_size, void* d_ws, size_t ws_size,
                              hipStream_t stream) {
    const int*   x      = (const int*)  d_in[0];
    const float* emb    = (const float*)d_in[1];
    const float* proj_w = (const float*)d_in[2];
    const float* proj_b = (const float*)d_in[3];
    const float* W_ih0  = (const float*)d_in[4];
    const float* W_hh0  = (const float*)d_in[5];
    const float* b_ih0  = (const float*)d_in[6];
    const float* b_hh0  = (const float*)d_in[7];
    const float* W_ih1  = (const float*)d_in[8];
    const float* W_hh1  = (const float*)d_in[9];
    const float* b_ih1  = (const float*)d_in[10];
    const float* b_hh1  = (const float*)d_in[11];
    float* out = (float*)d_out;

    char* ws = (char*)d_ws;
    f16* emb_sum = (f16*)(ws);                               // 32 MB [S,B,E]
    f16* x_in    = (f16*)(ws + 33554432ull);                 // 32 MB [S,B,E]
    f16* gates   = (f16*)(ws + 67108864ull);                 // 128 MB (128-step chunk)
    char* wp     = ws + 201326592ull;
    f16* pw_f   = (f16*)wp; wp += (size_t)Ee * Ee * 2;
    f16* wih0_f = (f16*)wp; wp += (size_t)FourH * Ee * 2;
    f16* whh0_f = (f16*)wp; wp += (size_t)FourH * Hh * 2;
    f16* wih1_f = (f16*)wp; wp += (size_t)FourH * Hh * 2;
    f16* whh1_f = (f16*)wp; wp += (size_t)FourH * Hh * 2;
    float* bias0 = (float*)wp; wp += FourH * 4;
    float* bias1 = (float*)wp; wp += FourH * 4;
    char* zbase = wp;
    f16*   h0r = (f16*)wp;   wp += 4ull * Bb * Hh * 2;       // 4-slot h0 ring
    f16*   h1a = (f16*)wp;   wp += (size_t)Bb * Hh * 2;
    f16*   h1b = (f16*)wp;   wp += (size_t)Bb * Hh * 2;
    float* c0  = (float*)wp; wp += (size_t)Bb * Hh * 4;
    float* c1  = (float*)wp; wp += (size_t)Bb * Hh * 4;
    unsigned* bar = (unsigned*)wp; wp += 4096;               // sync counters
    size_t zbytes = (size_t)(wp - zbase);

    // Prologue: converts, biases, zero state+counters
    cvt_f16_kernel<<<512, 256, 0, stream>>>(proj_w, pw_f,   Ee * Ee);
    cvt_f16_kernel<<<512, 256, 0, stream>>>(W_ih0,  wih0_f, FourH * Ee);
    cvt_f16_kernel<<<512, 256, 0, stream>>>(W_hh0,  whh0_f, FourH * Hh);
    cvt_f16_kernel<<<512, 256, 0, stream>>>(W_ih1,  wih1_f, FourH * Hh);
    cvt_f16_kernel<<<512, 256, 0, stream>>>(W_hh1,  whh1_f, FourH * Hh);
    bias_combine_kernel<<<32, 256, 0, stream>>>(b_ih0, b_hh0, b_ih1, b_hh1, bias0, bias1);
    hipMemsetAsync(zbase, 0, zbytes, stream);

    // Embedding + input projection (time-major)
    emb_kernel<<<Mrows, 256, 0, stream>>>(x, emb, emb_sum);
    gemm_bt_kernel<<<dim3(Ee / BN, Mrows / BM), 256, 0, stream>>>(
        emb_sum, pw_f, proj_b, x_in, Mrows, Ee, Ee);

    // Two half-sequence passes: gates0 GEMM chunk + cooperative scan
    const int CM = Mrows / 2;   // 16384 rows = 128 steps

    for (int half = 0; half < 2; ++half) {
        gemm_bt_kernel<<<dim3(FourH / BN, CM / BM), 256, 0, stream>>>(
            x_in + (size_t)half * CM * Ee, wih0_f, bias0, gates, CM, FourH, Ee);
        int tb = half * 128;
        int te = (half == 0) ? 128 : 257;   // second pass runs one extra L1-only iter
        const f16* gxp = gates;
        void* args[] = { (void*)&gxp, (void*)&tb, (void*)&te,
                         (void*)&wih1_f, (void*)&whh0_f, (void*)&whh1_f, (void*)&bias1,
                         (void*)&h0r, (void*)&h1a, (void*)&h1b,
                         (void*)&c0, (void*)&c1, (void*)&out, (void*)&bar };
        hipLaunchCooperativeKernel((const void*)scan_kernel, dim3(NBLK), dim3(512),
                                   args, 0, stream);
    }
}

// Round 9
// 2794.474 us; speedup vs baseline: 1.7509x; 1.0728x over previous
//
#include <hip/hip_runtime.h>
#include <hip/hip_bf16.h>

#define Bb    128
#define Ss    256
#define Ff    4
#define Vv    1024
#define Ee    512
#define Hh    1024
#define FourH 4096
#define Mrows (Bb * Ss)
#define NBLK  192      // 64 layer-0 WGs + 128 layer-1 WGs

typedef _Float16 f16;
typedef __attribute__((ext_vector_type(8))) _Float16 half8;
typedef __attribute__((ext_vector_type(4))) float f32x4;

// ---------------------------------------------------------------------------
__global__ void cvt_f16_kernel(const float* __restrict__ s, f16* __restrict__ d, int n) {
    int i = blockIdx.x * blockDim.x + threadIdx.x;
    int stride = gridDim.x * blockDim.x;
    for (; i < n; i += stride) d[i] = (f16)s[i];
}

__global__ void bias_combine_kernel(const float* __restrict__ a, const float* __restrict__ b,
                                    const float* __restrict__ c, const float* __restrict__ d,
                                    float* __restrict__ o0, float* __restrict__ o1) {
    int i = blockIdx.x * blockDim.x + threadIdx.x;
    if (i < FourH) o0[i] = a[i] + b[i];
    else if (i < 2 * FourH) { int j = i - FourH; o1[j] = c[j] + d[j]; }
}

// Embedding: sum over F tables -> f16 [S, B, E] (time-major)
__global__ void emb_kernel(const int* __restrict__ x, const float* __restrict__ emb,
                           f16* __restrict__ out) {
    int r = blockIdx.x;
    int t = threadIdx.x;
    int b = r / Ss, s = r % Ss;
    const int* xr = x + (size_t)r * Ff;
    const float* e0 = emb + (size_t)xr[0] * Ee;
    const float* e1 = emb + (size_t)(Vv + xr[1]) * Ee;
    const float* e2 = emb + (size_t)(2 * Vv + xr[2]) * Ee;
    const float* e3 = emb + (size_t)(3 * Vv + xr[3]) * Ee;
    f16* orow = out + (size_t)(s * Bb + b) * Ee;
    for (int e = t; e < Ee; e += 256) orow[e] = (f16)(e0[e] + e1[e] + e2[e] + e3[e]);
}

// ---------------------------------------------------------------------------
// C[M,N] = A[M,K] @ B[N,K]^T + bias[N]  (f16 in, f16 out, fp32 accum)
#define BM 128
#define BN 128
#define BK 32
#define LDP 40

__global__ __launch_bounds__(256) void gemm_bt_kernel(
    const f16* __restrict__ A, const f16* __restrict__ Bw,
    const float* __restrict__ bias, f16* __restrict__ C,
    int M, int N, int K)
{
    __shared__ f16 As[BM * LDP];
    __shared__ f16 Bs[BN * LDP];
    int tid  = threadIdx.x;
    int n0   = blockIdx.x * BN;
    int m0   = blockIdx.y * BM;
    int w    = tid >> 6, lane = tid & 63;
    int wm   = (w >> 1) * 64, wn = (w & 1) * 64;
    int lrow = lane & 15, koff = lane >> 4;

    f32x4 acc[4][4] = {};

    for (int kb = 0; kb < K; kb += BK) {
        __syncthreads();
        #pragma unroll
        for (int h = 0; h < 2; ++h) {
            int ch  = tid + h * 256;
            int row = ch >> 2;
            int cc  = (ch & 3) * 8;
            *reinterpret_cast<uint4*>(&As[row * LDP + cc]) =
                *reinterpret_cast<const uint4*>(A + (size_t)(m0 + row) * K + kb + cc);
            *reinterpret_cast<uint4*>(&Bs[row * LDP + cc]) =
                *reinterpret_cast<const uint4*>(Bw + (size_t)(n0 + row) * K + kb + cc);
        }
        __syncthreads();
        half8 af[4], bf[4];
        #pragma unroll
        for (int mt = 0; mt < 4; ++mt)
            af[mt] = *reinterpret_cast<const half8*>(&As[(wm + mt * 16 + lrow) * LDP + koff * 8]);
        #pragma unroll
        for (int nt = 0; nt < 4; ++nt)
            bf[nt] = *reinterpret_cast<const half8*>(&Bs[(wn + nt * 16 + lrow) * LDP + koff * 8]);
        #pragma unroll
        for (int mt = 0; mt < 4; ++mt)
            #pragma unroll
            for (int nt = 0; nt < 4; ++nt)
                acc[mt][nt] = __builtin_amdgcn_mfma_f32_16x16x32_f16(af[mt], bf[nt], acc[mt][nt], 0, 0, 0);
    }

    #pragma unroll
    for (int mt = 0; mt < 4; ++mt)
        #pragma unroll
        for (int nt = 0; nt < 4; ++nt) {
            int col = n0 + wn + nt * 16 + lrow;
            float bv = bias[col];
            #pragma unroll
            for (int r = 0; r < 4; ++r) {
                int rowg = m0 + wm + mt * 16 + koff * 4 + r;
                C[(size_t)rowg * N + col] = (f16)(acc[mt][nt][r] + bv);
            }
        }
}

// ---------------------------------------------------------------------------
__device__ __forceinline__ void gload_lds16(const void* g, void* l) {
    __builtin_amdgcn_global_load_lds((const __attribute__((address_space(1))) void*)g,
                                     (__attribute__((address_space(3))) void*)l, 16, 0, 0);
}

// Device-coherent 4B store: write-through past L1/L2 to the coherence point
// (MALL). Visible device-wide once vmcnt retires - no wbl2 fence needed.
__device__ __forceinline__ void gst_cc(void* p, unsigned v) {
    asm volatile("global_store_dword %0, %1, off sc0 sc1" :: "v"(p), "v"(v) : "memory");
}

__device__ __forceinline__ float f16lo(unsigned u) {
    return (float)__builtin_bit_cast(f16, (unsigned short)(u & 0xffffu));
}
__device__ __forceinline__ float f16hi(unsigned u) {
    return (float)__builtin_bit_cast(f16, (unsigned short)(u >> 16));
}

__device__ __forceinline__ unsigned aload(unsigned* p) {
    return __hip_atomic_load(p, __ATOMIC_RELAXED, __HIP_MEMORY_SCOPE_AGENT);
}

__device__ __forceinline__ float sigm(float v) { return 1.f / (1.f + __expf(-v)); }

// ---------------------------------------------------------------------------
// Persistent fused 2-layer LSTM scan, R9: L2-CACHED h BROADCAST.
// h0/h1 are 8-deep rings; the full-L2 acquire-inv runs only on iterations
// i%8==0. Ring depth >= inv period guarantees no stale L2 copy can exist
// (any cached ring line was loaded after the last inv => fresh version),
// so on 7 of 8 iterations the 96-way h broadcast per half is absorbed by
// the per-XCD L2s instead of hammering MALL (40 MB/iter -> ~5 MB/iter).
// Sync: decoupled per-half producer/consumer counters (R8, verified);
// h handoff: packed sc0/sc1 write-through stores + vmcnt(0) drain (R7).
__global__ __launch_bounds__(512, 2) __attribute__((amdgpu_waves_per_eu(2, 2)))
void scan_kernel(
    const f16* __restrict__ gx0,    // gates0 chunk base [nt][128][4096]
    int t_begin, int t_end,
    const f16* __restrict__ wih1, const f16* __restrict__ whh0,
    const f16* __restrict__ whh1, const float* __restrict__ bias1,
    f16* __restrict__ h0r,          // 8-slot ring [8][128][1024]
    f16* __restrict__ h1r,          // 8-slot ring [8][128][1024]
    float* __restrict__ c0, float* __restrict__ c1,
    float* __restrict__ out, unsigned* __restrict__ bar)
{
    __shared__ __align__(1024) char smem[131072];
    float* ep = (float*)smem;

    const int tid  = threadIdx.x;
    const int wg   = blockIdx.x;
    const int lane = tid & 63;
    const int w    = tid >> 6;
    const int lrow = lane & 15, koff = lane >> 4;
    const unsigned swz   = (unsigned)((lane & 7) << 4);
    const unsigned e0s   = ((unsigned)(koff * 16)) ^ swz;         // (kc&1)==0
    const unsigned e1s   = ((unsigned)(64 + koff * 16)) ^ swz;    // (kc&1)==1
    const unsigned lane16 = (unsigned)(lane << 4);
    const size_t HSLOT = (size_t)Bb * Hh;   // f16 elems per ring slot

    if (wg < 64) {
        // ---------------- Layer 0: rowg(2) x ug(32 units), waves np(4) x kh(2)
        const int rowg = wg >> 5, ug = wg & 31;
        const int np = w & 3, kh = w >> 2;
        const int u0 = ug * 32;
        const size_t growb = (size_t)rowg * 64;
        const int cw = np * 32 + lrow;         // + nt*16

        unsigned* arr0 = bar + (0 + rowg) * 32;   // L0 arrivals (this half)
        unsigned* rel0 = bar + (2 + rowg) * 32;   // L0 release == L0_done
        unsigned* rel1 = bar + (6 + rowg) * 32;   // L1_done (read-only here)

        half8 wreg[16][2];
        #pragma unroll
        for (int kc = 0; kc < 16; ++kc)
            #pragma unroll
            for (int nt = 0; nt < 2; ++nt) {
                int c = cw + nt * 16;
                wreg[kc][nt] = *(const half8*)(whh0
                    + (size_t)((c >> 5) * Hh + u0 + (c & 31)) * Hh
                    + kh * 512 + kc * 32 + koff * 8);
            }

        float creg[2][2];
        #pragma unroll
        for (int q = 0; q < 2; ++q) {
            int p = tid + q * 512, row = p >> 4, up = p & 15;
            float2 cc = *(const float2*)&c0[(growb + row) * Hh + u0 + 2 * up];
            creg[q][0] = cc.x; creg[q][1] = cc.y;
        }

        for (int i = t_begin; i < t_end; ++i) {
            if (i < 256) {
                const f16* hp = h0r + (size_t)((unsigned)((i - 1) & 7)) * HSLOT; // h0[i-1]
                f16*       hw = h0r + (size_t)(i & 7) * HSLOT;                   // h0[i]
                const f16* gx = gx0 + (size_t)(i - t_begin) * (Bb * FourH);
                const char* hb = (const char*)hp + growb * 2048;

                // gate-input prefetch, 2 f16 packed per gate (plain cached loads)
                unsigned gxu[2][4];
                #pragma unroll
                for (int q = 0; q < 2; ++q) {
                    int p = tid + q * 512, row = p >> 4, up = p & 15;
                    const unsigned* gr = (const unsigned*)(gx + (growb + row) * FourH + u0) + up;
                    gxu[q][0] = gr[0];
                    gxu[q][1] = gr[512];
                    gxu[q][2] = gr[1024];
                    gxu[q][3] = gr[1536];
                }

                // single-shot stage: 64 rows x 2048 B (16 instr/wave)
                #pragma unroll
                for (int t = 0; t < 16; ++t) {
                    int row  = w * 8 + (t >> 1);
                    int half = t & 1;
                    gload_lds16(hb + (size_t)row * 2048 + half * 1024
                                   + (lane16 ^ ((unsigned)((row & 7) << 4))),
                                smem + row * 2048 + half * 1024);
                }

                asm volatile("s_waitcnt vmcnt(0)" ::: "memory");
                __syncthreads();

                f32x4 acc[4][2] = {};
                #pragma unroll
                for (int kc = 0; kc < 16; ++kc) {
                    unsigned off = (unsigned)(kh * 1024 + (kc >> 1) * 128)
                                 + ((kc & 1) ? e1s : e0s);
                    half8 a[4];
                    #pragma unroll
                    for (int mt = 0; mt < 4; ++mt)
                        a[mt] = *(const half8*)(smem + (mt * 16 + lrow) * 2048 + off);
                    #pragma unroll
                    for (int mt = 0; mt < 4; ++mt) {
                        acc[mt][0] = __builtin_amdgcn_mfma_f32_16x16x32_f16(a[mt], wreg[kc][0], acc[mt][0], 0, 0, 0);
                        acc[mt][1] = __builtin_amdgcn_mfma_f32_16x16x32_f16(a[mt], wreg[kc][1], acc[mt][1], 0, 0, 0);
                    }
                }
                __syncthreads();           // staging reads done before ep overwrite
                // ep[kh][row][c] : [2][64][128]
                #pragma unroll
                for (int mt = 0; mt < 4; ++mt)
                    #pragma unroll
                    for (int nt = 0; nt < 2; ++nt) {
                        int c = cw + nt * 16;
                        int rowb = mt * 16 + koff * 4;
                        #pragma unroll
                        for (int r = 0; r < 4; ++r)
                            ep[(kh * 64 + rowb + r) * 128 + c] = acc[mt][nt][r];
                    }
                // WAR gate on h0 ring slot i&7: old content h0[i-8] was consumed
                // by L1 at its iteration i-7 -> rel1 >= i-6. Overlapped here.
                if (tid == 0) {
                    while ((int)aload(rel1) < i - 6) __builtin_amdgcn_s_sleep(2);
                }
                __syncthreads();
                #pragma unroll
                for (int q = 0; q < 2; ++q) {
                    int p = tid + q * 512, row = p >> 4, up = p & 15, uu = 2 * up;
                    float2 iP = *(const float2*)&ep[row * 128 + uu];
                    float2 iQ = *(const float2*)&ep[(64 + row) * 128 + uu];
                    float2 fP = *(const float2*)&ep[row * 128 + 32 + uu];
                    float2 fQ = *(const float2*)&ep[(64 + row) * 128 + 32 + uu];
                    float2 gP = *(const float2*)&ep[row * 128 + 64 + uu];
                    float2 gQ = *(const float2*)&ep[(64 + row) * 128 + 64 + uu];
                    float2 oP = *(const float2*)&ep[row * 128 + 96 + uu];
                    float2 oQ = *(const float2*)&ep[(64 + row) * 128 + 96 + uu];
                    float ip0 = iP.x + iQ.x + f16lo(gxu[q][0]);
                    float ip1 = iP.y + iQ.y + f16hi(gxu[q][0]);
                    float fp0 = fP.x + fQ.x + f16lo(gxu[q][1]);
                    float fp1 = fP.y + fQ.y + f16hi(gxu[q][1]);
                    float gp0 = gP.x + gQ.x + f16lo(gxu[q][2]);
                    float gp1 = gP.y + gQ.y + f16hi(gxu[q][2]);
                    float op0 = oP.x + oQ.x + f16lo(gxu[q][3]);
                    float op1 = oP.y + oQ.y + f16hi(gxu[q][3]);
                    float cn0 = sigm(fp0) * creg[q][0] + sigm(ip0) * tanhf(gp0);
                    float cn1 = sigm(fp1) * creg[q][1] + sigm(ip1) * tanhf(gp1);
                    creg[q][0] = cn0; creg[q][1] = cn1;
                    f16 hA = (f16)(sigm(op0) * tanhf(cn0));
                    f16 hB = (f16)(sigm(op1) * tanhf(cn1));
                    unsigned hv = (unsigned)__builtin_bit_cast(unsigned short, hA)
                                | ((unsigned)__builtin_bit_cast(unsigned short, hB) << 16);
                    gst_cc((void*)(hw + (growb + row) * Hh + u0 + uu), hv);
                }
            }
            // ---- L0 internal 32-WG barrier (rel0 doubles as L0_done) ----
            asm volatile("s_waitcnt vmcnt(0)" ::: "memory");   // h0 stores at MALL
            __syncthreads();
            if (tid == 0) {
                unsigned a = atomicAdd(arr0, 1u);
                unsigned gen = a >> 5;
                if ((a & 31u) == 31u) atomicAdd(rel0, 1u);
                while (aload(rel0) < gen + 1u) __builtin_amdgcn_s_sleep(2);
                if ((i & 7) == 0)
                    __builtin_amdgcn_fence(__ATOMIC_ACQUIRE, "agent");  // periodic L2 inv
            }
            __syncthreads();
        }
        #pragma unroll
        for (int q = 0; q < 2; ++q) {
            int p = tid + q * 512, row = p >> 4, up = p & 15;
            *(float2*)&c0[(growb + row) * Hh + u0 + 2 * up] = make_float2(creg[q][0], creg[q][1]);
        }
    } else {
        // ---------------- Layer 1: rowg(2) x ug(64; 16 units), waves = pure kq(8)
        const int wgl = wg - 64;
        const int rowg = wgl >> 6, ug = wgl & 63;
        const int kq = w;                      // 0..7 : K-window kq*256 of 2048
        const int u0 = ug * 16;
        const size_t growb = (size_t)rowg * 64;
        const int l7 = lane & 7;

        unsigned* arr1 = bar + (4 + rowg) * 32;   // L1 arrivals (this half)
        unsigned* rel1 = bar + (6 + rowg) * 32;   // L1 release == L1_done
        unsigned* rel0 = bar + (2 + rowg) * 32;   // L0_done (read-only here)

        const f16* wbase = (kq < 4) ? wih1 : whh1;
        half8 wreg[8][4];                      // [kc][nt], K = (kq&3)*256 + kc*32
        #pragma unroll
        for (int kc = 0; kc < 8; ++kc)
            #pragma unroll
            for (int nt = 0; nt < 4; ++nt)     // col = nt*16+lrow: gate=nt, unit=lrow
                wreg[kc][nt] = *(const half8*)(wbase
                    + (size_t)(nt * Hh + u0 + lrow) * Hh
                    + (kq & 3) * 256 + kc * 32 + koff * 8);

        const int erow = tid >> 3, eup = tid & 7, euu = 2 * eup;
        float crg0, crg1;
        { float2 cc = *(const float2*)&c1[(growb + erow) * Hh + u0 + euu];
          crg0 = cc.x; crg1 = cc.y; }
        float2 bI = *(const float2*)&bias1[u0 + euu];
        float2 bF = *(const float2*)&bias1[Hh + u0 + euu];
        float2 bG = *(const float2*)&bias1[2 * Hh + u0 + euu];
        float2 bO = *(const float2*)&bias1[3 * Hh + u0 + euu];

        const unsigned wb = (unsigned)kq * 16384u;   // this wave's 16 KB LDS slab
        const int r2 = lane >> 5;                    // 0/1 (row parity per instr)
        const int chs0 = lane & 31;                  // 16B-chunk slot in 512B row

        #define STG(rb_, bo_) { \
            _Pragma("unroll") \
            for (int t = 0; t < 8; ++t) { \
                int rl = (rb_) + t * 2 + r2; \
                gload_lds16(src + (size_t)rl * 2048 \
                                + ((unsigned)((chs0 ^ (rl & 7)) << 4)), \
                            smem + wb + (bo_) + (unsigned)(t * 1024)); \
            } }
        #define CMT(mt_, bo_) { \
            _Pragma("unroll") \
            for (int kc = 0; kc < 8; ++kc) { \
                half8 a = *(const half8*)(smem + wb + (bo_) \
                            + (unsigned)(lrow * 512) \
                            + ((unsigned)(((kc * 4 + koff) ^ l7) << 4))); \
                acc[mt_][0] = __builtin_amdgcn_mfma_f32_16x16x32_f16(a, wreg[kc][0], acc[mt_][0], 0, 0, 0); \
                acc[mt_][1] = __builtin_amdgcn_mfma_f32_16x16x32_f16(a, wreg[kc][1], acc[mt_][1], 0, 0, 0); \
                acc[mt_][2] = __builtin_amdgcn_mfma_f32_16x16x32_f16(a, wreg[kc][2], acc[mt_][2], 0, 0, 0); \
                acc[mt_][3] = __builtin_amdgcn_mfma_f32_16x16x32_f16(a, wreg[kc][3], acc[mt_][3], 0, 0, 0); \
            } }

        for (int i = t_begin; i < t_end; ++i) {
            int t1 = i - 1;
            if (t1 >= 0) {
                // Data gate: h0[t1] complete once rel0 >= i. Periodic acquire-inv
                // AFTER the gate (only on inv iterations).
                if (tid == 0) {
                    while ((int)aload(rel0) < i) __builtin_amdgcn_s_sleep(2);
                    if ((i & 7) == 0)
                        __builtin_amdgcn_fence(__ATOMIC_ACQUIRE, "agent");
                }
                __syncthreads();

                const f16* a0 = h0r + (size_t)(t1 & 7) * HSLOT;               // h0[t1]
                const f16* a1 = h1r + (size_t)((unsigned)((t1 - 1) & 7)) * HSLOT; // h1[t1-1]
                f16*       hw = h1r + (size_t)(t1 & 7) * HSLOT;               // h1[t1]
                const char* src = ((kq < 4) ? (const char*)a0 : (const char*)a1)
                                + growb * 2048 + (size_t)(kq & 3) * 512;

                f32x4 acc[4][4] = {};
                STG(0, 0u)
                STG(16, 8192u)
                asm volatile("s_waitcnt vmcnt(8)" ::: "memory");   // rows 0-15 in
                CMT(0, 0u)
                asm volatile("s_waitcnt lgkmcnt(0)" ::: "memory"); // buf0 reads done
                STG(32, 0u)
                asm volatile("s_waitcnt vmcnt(8)" ::: "memory");   // rows 16-31 in
                CMT(1, 8192u)
                asm volatile("s_waitcnt lgkmcnt(0)" ::: "memory"); // buf1 reads done
                STG(48, 8192u)
                asm volatile("s_waitcnt vmcnt(8)" ::: "memory");   // rows 32-47 in
                CMT(2, 0u)
                asm volatile("s_waitcnt vmcnt(0)" ::: "memory");   // rows 48-63 in
                CMT(3, 8192u)

                // ep partials into OWN slab (64 rows x 64 cols f32 = 16 KB).
                // layout: slab[row*256 + (c ^ (sw<<4))*4], sw=(row^(row>>2))&3
                #pragma unroll
                for (int mt = 0; mt < 4; ++mt)
                    #pragma unroll
                    for (int nt = 0; nt < 4; ++nt) {
                        int c = nt * 16 + lrow;
                        #pragma unroll
                        for (int r = 0; r < 4; ++r) {
                            int row = mt * 16 + koff * 4 + r;
                            int sw  = (row ^ (row >> 2)) & 3;
                            *(float*)(smem + wb + (unsigned)(row * 256)
                                      + (unsigned)((c ^ (sw << 4)) * 4)) = acc[mt][nt][r];
                        }
                    }
                __syncthreads();
                {
                    int sw = (erow ^ (erow >> 2)) & 3;
                    const char* rbase = smem + (unsigned)(erow * 256);
                    float s0x = bI.x, s0y = bI.y, s1x = bF.x, s1y = bF.y;
                    float s2x = bG.x, s2y = bG.y, s3x = bO.x, s3y = bO.y;
                    #pragma unroll
                    for (int k8 = 0; k8 < 8; ++k8) {
                        const char* base = rbase + (unsigned)k8 * 16384u;
                        float2 v0 = *(const float2*)(base + (unsigned)((( 0 + euu) ^ (sw << 4)) * 4));
                        float2 v1 = *(const float2*)(base + (unsigned)(((16 + euu) ^ (sw << 4)) * 4));
                        float2 v2 = *(const float2*)(base + (unsigned)(((32 + euu) ^ (sw << 4)) * 4));
                        float2 v3 = *(const float2*)(base + (unsigned)(((48 + euu) ^ (sw << 4)) * 4));
                        s0x += v0.x; s0y += v0.y; s1x += v1.x; s1y += v1.y;
                        s2x += v2.x; s2y += v2.y; s3x += v3.x; s3y += v3.y;
                    }
                    float cn0 = sigm(s1x) * crg0 + sigm(s0x) * tanhf(s2x); crg0 = cn0;
                    float cn1 = sigm(s1y) * crg1 + sigm(s0y) * tanhf(s2y); crg1 = cn1;
                    float hn0 = sigm(s3x) * tanhf(cn0);
                    float hn1 = sigm(s3y) * tanhf(cn1);
                    unsigned hv = (unsigned)__builtin_bit_cast(unsigned short, (f16)hn0)
                                | ((unsigned)__builtin_bit_cast(unsigned short, (f16)hn1) << 16);
                    gst_cc((void*)(hw + (growb + erow) * Hh + u0 + euu), hv);
                    *(float2*)&out[(growb + erow) * (size_t)(Ss * Hh)
                                   + (size_t)t1 * Hh + u0 + euu] = make_float2(hn0, hn1);
                }
            }
            // ---- L1 internal 64-WG barrier (rel1 doubles as L1_done) ----
            asm volatile("s_waitcnt vmcnt(0)" ::: "memory");   // h1 stores at MALL
            __syncthreads();
            if (tid == 0) {
                unsigned a = atomicAdd(arr1, 1u);
                unsigned gen = a >> 6;
                if ((a & 63u) == 63u) atomicAdd(rel1, 1u);
                while (aload(rel1) < gen + 1u) __builtin_amdgcn_s_sleep(2);
            }
            __syncthreads();
        }
        *(float2*)&c1[(growb + erow) * Hh + u0 + euu] = make_float2(crg0, crg1);
        #undef STG
        #undef CMT
    }
}

// ---------------------------------------------------------------------------
extern "C" void kernel_launch(void* const* d_in, const int* in_sizes, int n_in,
                              void* d_out, int out_size, void* d_ws, size_t ws_size,
                              hipStream_t stream) {
    const int*   x      = (const int*)  d_in[0];
    const float* emb    = (const float*)d_in[1];
    const float* proj_w = (const float*)d_in[2];
    const float* proj_b = (const float*)d_in[3];
    const float* W_ih0  = (const float*)d_in[4];
    const float* W_hh0  = (const float*)d_in[5];
    const float* b_ih0  = (const float*)d_in[6];
    const float* b_hh0  = (const float*)d_in[7];
    const float* W_ih1  = (const float*)d_in[8];
    const float* W_hh1  = (const float*)d_in[9];
    const float* b_ih1  = (const float*)d_in[10];
    const float* b_hh1  = (const float*)d_in[11];
    float* out = (float*)d_out;

    char* ws = (char*)d_ws;
    f16* emb_sum = (f16*)(ws);                               // 32 MB [S,B,E]
    f16* x_in    = (f16*)(ws + 33554432ull);                 // 32 MB [S,B,E]
    f16* gates   = (f16*)(ws + 67108864ull);                 // 128 MB (128-step chunk)
    char* wp     = ws + 201326592ull;
    f16* pw_f   = (f16*)wp; wp += (size_t)Ee * Ee * 2;
    f16* wih0_f = (f16*)wp; wp += (size_t)FourH * Ee * 2;
    f16* whh0_f = (f16*)wp; wp += (size_t)FourH * Hh * 2;
    f16* wih1_f = (f16*)wp; wp += (size_t)FourH * Hh * 2;
    f16* whh1_f = (f16*)wp; wp += (size_t)FourH * Hh * 2;
    float* bias0 = (float*)wp; wp += FourH * 4;
    float* bias1 = (float*)wp; wp += FourH * 4;
    char* zbase = wp;
    f16*   h0r = (f16*)wp;   wp += 8ull * Bb * Hh * 2;       // 8-slot h0 ring
    f16*   h1r = (f16*)wp;   wp += 8ull * Bb * Hh * 2;       // 8-slot h1 ring
    float* c0  = (float*)wp; wp += (size_t)Bb * Hh * 4;
    float* c1  = (float*)wp; wp += (size_t)Bb * Hh * 4;
    unsigned* bar = (unsigned*)wp; wp += 4096;               // sync counters
    size_t zbytes = (size_t)(wp - zbase);

    // Prologue: converts, biases, zero state+counters
    cvt_f16_kernel<<<512, 256, 0, stream>>>(proj_w, pw_f,   Ee * Ee);
    cvt_f16_kernel<<<512, 256, 0, stream>>>(W_ih0,  wih0_f, FourH * Ee);
    cvt_f16_kernel<<<512, 256, 0, stream>>>(W_hh0,  whh0_f, FourH * Hh);
    cvt_f16_kernel<<<512, 256, 0, stream>>>(W_ih1,  wih1_f, FourH * Hh);
    cvt_f16_kernel<<<512, 256, 0, stream>>>(W_hh1,  whh1_f, FourH * Hh);
    bias_combine_kernel<<<32, 256, 0, stream>>>(b_ih0, b_hh0, b_ih1, b_hh1, bias0, bias1);
    hipMemsetAsync(zbase, 0, zbytes, stream);

    // Embedding + input projection (time-major)
    emb_kernel<<<Mrows, 256, 0, stream>>>(x, emb, emb_sum);
    gemm_bt_kernel<<<dim3(Ee / BN, Mrows / BM), 256, 0, stream>>>(
        emb_sum, pw_f, proj_b, x_in, Mrows, Ee, Ee);

    // Two half-sequence passes: gates0 GEMM chunk + cooperative scan
    const int CM = Mrows / 2;   // 16384 rows = 128 steps

    for (int half = 0; half < 2; ++half) {
        gemm_bt_kernel<<<dim3(FourH / BN, CM / BM), 256, 0, stream>>>(
            x_in + (size_t)half * CM * Ee, wih0_f, bias0, gates, CM, FourH, Ee);
        int tb = half * 128;
        int te = (half == 0) ? 128 : 257;   // second pass runs one extra L1-only iter
        const f16* gxp = gates;
        void* args[] = { (void*)&gxp, (void*)&tb, (void*)&te,
                         (void*)&wih1_f, (void*)&whh0_f, (void*)&whh1_f, (void*)&bias1,
                         (void*)&h0r, (void*)&h1r,
                         (void*)&c0, (void*)&c1, (void*)&out, (void*)&bar };
        hipLaunchCooperativeKernel((const void*)scan_kernel, dim3(NBLK), dim3(512),
                                   args, 0, stream);
    }
}